// Round 1
// baseline (3713.006 us; speedup 1.0000x reference)
//
#include <hip/hip_runtime.h>
#include <cstdint>
#include <cstddef>

// =====================================================================
// LENet block: x = MHA(LN(q), LN(kv)) + q ; x = MHA(LN(x),LN(x)) + x ;
//              x = NoisyTop2MoE(LN(x)) + x
// Round 1: all-fp32 (routing needs ~1e-5 accuracy on the x path; bf16
// would flip top-2 selections and blow the 0.1075 absmax threshold).
// PRNG: JAX threefry2x32, partitionable counter mode (default since
// JAX 0.4.30). Flip macro below to the legacy iota-split path if this
// round shows O(1) absmax (= mass routing mismatch).
// =====================================================================
#define JAX_THREEFRY_PARTITIONABLE 1

__device__ __forceinline__ int imin_(int a, int b) { return a < b ? a : b; }

// ---------------- threefry2x32 (JAX-exact, 20 rounds) ----------------
__device__ __forceinline__ unsigned rotl32_(unsigned v, int d) {
  return (v << d) | (v >> (32 - d));
}

__device__ __forceinline__ void threefry2x32_(unsigned k0, unsigned k1,
                                              unsigned x0, unsigned x1,
                                              unsigned& o0, unsigned& o1) {
  unsigned ks2 = k0 ^ k1 ^ 0x1BD11BDAu;
  x0 += k0; x1 += k1;
#define TF_R(rot) { x0 += x1; x1 = rotl32_(x1, rot); x1 ^= x0; }
  TF_R(13) TF_R(15) TF_R(26) TF_R(6)
  x0 += k1;  x1 += ks2 + 1u;
  TF_R(17) TF_R(29) TF_R(16) TF_R(24)
  x0 += ks2; x1 += k0 + 2u;
  TF_R(13) TF_R(15) TF_R(26) TF_R(6)
  x0 += k0;  x1 += k1 + 3u;
  TF_R(17) TF_R(29) TF_R(16) TF_R(24)
  x0 += k1;  x1 += ks2 + 4u;
  TF_R(13) TF_R(15) TF_R(26) TF_R(6)
  x0 += ks2; x1 += k0 + 5u;
#undef TF_R
  o0 = x0; o1 = x1;
}

// XLA ErfInv32 (Giles polynomial) — matches lax.erf_inv on f32.
__device__ float erfinv_f32_(float x) {
  float w = -log1pf(-x * x);
  float p;
  if (w < 5.0f) {
    w -= 2.5f;
    p = 2.81022636e-08f;
    p = fmaf(p, w, 3.43273939e-07f);
    p = fmaf(p, w, -3.5233877e-06f);
    p = fmaf(p, w, -4.39150654e-06f);
    p = fmaf(p, w, 0.00021858087f);
    p = fmaf(p, w, -0.00125372503f);
    p = fmaf(p, w, -0.00417768164f);
    p = fmaf(p, w, 0.246640727f);
    p = fmaf(p, w, 1.50140941f);
  } else {
    w = sqrtf(w) - 3.0f;
    p = -0.000200214257f;
    p = fmaf(p, w, 0.000100950558f);
    p = fmaf(p, w, 0.00134934322f);
    p = fmaf(p, w, -0.00367342844f);
    p = fmaf(p, w, 0.00573950773f);
    p = fmaf(p, w, -0.0076224613f);
    p = fmaf(p, w, 0.00943887047f);
    p = fmaf(p, w, 1.00167406f);
    p = fmaf(p, w, 2.83297682f);
  }
  return p * x;
}

// jax.random.normal mapping: u = uniform(lo=nextafter(-1,0), hi=1);
// (hi-lo) rounds to exactly 2.0f in f32. n = sqrt(2)*erfinv(u).
__device__ float bits_to_normal_(unsigned b) {
  const float lo = -0.99999994f;  // nextafter(-1, 0) in f32
  float f = __uint_as_float((b >> 9) | 0x3f800000u) - 1.0f;  // [0,1)
  float u = fmaxf(lo, f * 2.0f + lo);
  return 1.41421356237f * erfinv_f32_(u);  // f32(sqrt(2)) = 0x3FB504F3
}

// normals for logits shape (2,1024,8) -> 16384 elems, key = (0,42)
__global__ __launch_bounds__(256) void noise_kernel(float* __restrict__ normals) {
  int i = blockIdx.x * 256 + threadIdx.x;   // grid 64 -> 16384 threads
#if JAX_THREEFRY_PARTITIONABLE
  if (i < 16384) {
    unsigned o0, o1;
    threefry2x32_(0u, 42u, 0u, (unsigned)i, o0, o1);  // counter = 64-bit flat idx
    normals[i] = bits_to_normal_(o0 ^ o1);
  }
#else
  if (i < 8192) {  // legacy: iota split in half, (x0,x1)=(i, i+8192)
    unsigned o0, o1;
    threefry2x32_(0u, 42u, (unsigned)i, (unsigned)(i + 8192), o0, o1);
    normals[i] = bits_to_normal_(o0);
    normals[i + 8192] = bits_to_normal_(o1);
  }
#endif
}

// ---------------- block reduce (256 threads, wave64) -----------------
__device__ float block_reduce_sum_(float v) {
  for (int m = 1; m <= 32; m <<= 1) v += __shfl_xor(v, m, 64);
  __shared__ float red[4];
  int lane = threadIdx.x & 63, w = threadIdx.x >> 6;
  if (lane == 0) red[w] = v;
  __syncthreads();
  v = red[0] + red[1] + red[2] + red[3];
  __syncthreads();
  return v;
}

// ---------------- LayerNorm over last dim (1024) ---------------------
__global__ __launch_bounds__(256) void ln_kernel(
    const float* __restrict__ X, const float* __restrict__ g,
    const float* __restrict__ bta, float* __restrict__ Y) {
  int row = blockIdx.x;
  int t = threadIdx.x;
  const float4* xr = (const float4*)(X + (size_t)row * 1024);
  float4 v = xr[t];
  float s = v.x + v.y + v.z + v.w;
  s = block_reduce_sum_(s);
  float mean = s * (1.0f / 1024.0f);
  float dx = v.x - mean, dy = v.y - mean, dz = v.z - mean, dw = v.w - mean;
  float sq = dx * dx + dy * dy + dz * dz + dw * dw;
  sq = block_reduce_sum_(sq);
  float rstd = 1.0f / sqrtf(sq * (1.0f / 1024.0f) + 1e-5f);
  float4 gv = ((const float4*)g)[t];
  float4 bv = ((const float4*)bta)[t];
  float4 y;
  y.x = dx * rstd * gv.x + bv.x;
  y.y = dy * rstd * gv.y + bv.y;
  y.z = dz * rstd * gv.z + bv.z;
  y.w = dw * rstd * gv.w + bv.w;
  ((float4*)(Y + (size_t)row * 1024))[t] = y;
}

// ---------------- fp32 tiled GEMM: C = A(MxK) @ W(NxK)^T + bias ------
// 128x128 tile, BK=16, 256 threads, 8x8 micro-tile (split 4+4 to keep
// LDS reads 2-way-max bank aliasing = free on CDNA4).
template<bool RESID>
__global__ __launch_bounds__(256) void gemm_nt(
    const float* __restrict__ A, const float* __restrict__ W,
    const float* __restrict__ bias, const float* __restrict__ resid,
    float* __restrict__ C, int M, int N, int K) {
  __shared__ float As[16][132];
  __shared__ float Bs[16][132];
  const int t = threadIdx.x;
  const int tx = t & 15, ty = t >> 4;
  const int n0 = blockIdx.x * 128, m0 = blockIdx.y * 128;
  float acc[8][8] = {};
  const int r = t >> 1, kk = (t & 1) * 8;
  const float* asrc = A + (size_t)(m0 + r) * K + kk;
  const float* wsrc = W + (size_t)(n0 + r) * K + kk;
  for (int k0 = 0; k0 < K; k0 += 16) {
    float4 a0 = *(const float4*)(asrc);
    float4 a1 = *(const float4*)(asrc + 4);
    float4 b0 = *(const float4*)(wsrc);
    float4 b1 = *(const float4*)(wsrc + 4);
    asrc += 16; wsrc += 16;
    As[kk + 0][r] = a0.x; As[kk + 1][r] = a0.y; As[kk + 2][r] = a0.z; As[kk + 3][r] = a0.w;
    As[kk + 4][r] = a1.x; As[kk + 5][r] = a1.y; As[kk + 6][r] = a1.z; As[kk + 7][r] = a1.w;
    Bs[kk + 0][r] = b0.x; Bs[kk + 1][r] = b0.y; Bs[kk + 2][r] = b0.z; Bs[kk + 3][r] = b0.w;
    Bs[kk + 4][r] = b1.x; Bs[kk + 5][r] = b1.y; Bs[kk + 6][r] = b1.z; Bs[kk + 7][r] = b1.w;
    __syncthreads();
#pragma unroll
    for (int k = 0; k < 16; ++k) {
      float a[8], bb[8];
      *(float4*)&a[0]  = *(const float4*)&As[k][ty * 4];
      *(float4*)&a[4]  = *(const float4*)&As[k][64 + ty * 4];
      *(float4*)&bb[0] = *(const float4*)&Bs[k][tx * 4];
      *(float4*)&bb[4] = *(const float4*)&Bs[k][64 + tx * 4];
#pragma unroll
      for (int i = 0; i < 8; ++i) {
#pragma unroll
        for (int j = 0; j < 8; ++j) acc[i][j] += a[i] * bb[j];
      }
    }
    __syncthreads();
  }
  float4 bs0 = *(const float4*)&bias[n0 + tx * 4];
  float4 bs1 = *(const float4*)&bias[n0 + 64 + tx * 4];
  float bb[8] = {bs0.x, bs0.y, bs0.z, bs0.w, bs1.x, bs1.y, bs1.z, bs1.w};
#pragma unroll
  for (int i = 0; i < 8; ++i) {
    int m = m0 + ((i < 4) ? (ty * 4 + i) : (64 + ty * 4 + i - 4));
    float* crow = C + (size_t)m * N + n0;
    float v[8];
#pragma unroll
    for (int j = 0; j < 8; ++j) v[j] = acc[i][j] + bb[j];
    if (RESID) {
      const float* rrow = resid + (size_t)m * N + n0;
      float4 r0 = *(const float4*)(rrow + tx * 4);
      float4 r1 = *(const float4*)(rrow + 64 + tx * 4);
      v[0] += r0.x; v[1] += r0.y; v[2] += r0.z; v[3] += r0.w;
      v[4] += r1.x; v[5] += r1.y; v[6] += r1.z; v[7] += r1.w;
    }
    *(float4*)(crow + tx * 4)      = *(float4*)&v[0];
    *(float4*)(crow + 64 + tx * 4) = *(float4*)&v[4];
  }
}

// ---------------- flash attention, fp32, DH=64 -----------------------
// grid (B*H, nq/64). K stored transposed in LDS so all inner reads are
// conflict-free-ish float4.  scale folded into q load (1/8).
__global__ __launch_bounds__(256) void attn_kernel(
    const float* __restrict__ QP, const float* __restrict__ KP,
    const float* __restrict__ VP, float* __restrict__ AO,
    int nq, int nkv) {
  __shared__ float qs[64][68];
  __shared__ float kst[64][68];  // [d][kv]
  __shared__ float vs[64][68];   // [kv][d]
  __shared__ float ps[64][68];   // [qrow][kv]
  const int t = threadIdx.x;
  const int tx = t & 15, ty = t >> 4;
  const int bh = blockIdx.x;
  const int b = bh >> 4, h = bh & 15;
  const int q0 = blockIdx.y * 64;
  {
    int r = t >> 2, c = (t & 3) * 16;
    const float* src = QP + (size_t)(b * nq + q0 + r) * 1024 + h * 64 + c;
#pragma unroll
    for (int j = 0; j < 4; ++j) {
      float4 v = *(const float4*)(src + 4 * j);
      v.x *= 0.125f; v.y *= 0.125f; v.z *= 0.125f; v.w *= 0.125f;
      *(float4*)&qs[r][c + 4 * j] = v;
    }
  }
  float o[4][4] = {};
  float mi[4] = {-INFINITY, -INFINITY, -INFINITY, -INFINITY};
  float li[4] = {};
  for (int kv0 = 0; kv0 < nkv; kv0 += 64) {
    {
      int r = t >> 2, c = (t & 3) * 16;
      const float* ksrc = KP + (size_t)(b * nkv + kv0 + r) * 1024 + h * 64 + c;
      const float* vsrc = VP + (size_t)(b * nkv + kv0 + r) * 1024 + h * 64 + c;
#pragma unroll
      for (int j = 0; j < 4; ++j) {
        float4 kvv = *(const float4*)(ksrc + 4 * j);
        kst[c + 4 * j + 0][r] = kvv.x;
        kst[c + 4 * j + 1][r] = kvv.y;
        kst[c + 4 * j + 2][r] = kvv.z;
        kst[c + 4 * j + 3][r] = kvv.w;
        *(float4*)&vs[r][c + 4 * j] = *(const float4*)(vsrc + 4 * j);
      }
    }
    __syncthreads();
    float s[4][4] = {};
#pragma unroll
    for (int d = 0; d < 64; d += 4) {
      float qa[4][4], kb[4][4];
#pragma unroll
      for (int i = 0; i < 4; ++i) *(float4*)qa[i] = *(const float4*)&qs[ty * 4 + i][d];
#pragma unroll
      for (int dd = 0; dd < 4; ++dd) *(float4*)kb[dd] = *(const float4*)&kst[d + dd][tx * 4];
#pragma unroll
      for (int i = 0; i < 4; ++i) {
#pragma unroll
        for (int j = 0; j < 4; ++j) {
#pragma unroll
          for (int dd = 0; dd < 4; ++dd) s[i][j] += qa[i][dd] * kb[dd][j];
        }
      }
    }
    float al[4];
#pragma unroll
    for (int i = 0; i < 4; ++i) {
      float rm = fmaxf(fmaxf(s[i][0], s[i][1]), fmaxf(s[i][2], s[i][3]));
      rm = fmaxf(rm, __shfl_xor(rm, 1, 64));
      rm = fmaxf(rm, __shfl_xor(rm, 2, 64));
      rm = fmaxf(rm, __shfl_xor(rm, 4, 64));
      rm = fmaxf(rm, __shfl_xor(rm, 8, 64));
      float mnew = fmaxf(mi[i], rm);
      al[i] = expf(mi[i] - mnew);   // first iter: exp(-inf) = 0
      float rs = 0.0f;
#pragma unroll
      for (int j = 0; j < 4; ++j) { s[i][j] = expf(s[i][j] - mnew); rs += s[i][j]; }
      rs += __shfl_xor(rs, 1, 64);
      rs += __shfl_xor(rs, 2, 64);
      rs += __shfl_xor(rs, 4, 64);
      rs += __shfl_xor(rs, 8, 64);
      li[i] = li[i] * al[i] + rs;
      mi[i] = mnew;
      *(float4*)&ps[ty * 4 + i][tx * 4] = *(float4*)s[i];
    }
#pragma unroll
    for (int i = 0; i < 4; ++i) {
#pragma unroll
      for (int j = 0; j < 4; ++j) o[i][j] *= al[i];
    }
    __syncthreads();
#pragma unroll
    for (int kkk = 0; kkk < 64; kkk += 4) {
      float pa[4][4], vb[4][4];
#pragma unroll
      for (int i = 0; i < 4; ++i) *(float4*)pa[i] = *(const float4*)&ps[ty * 4 + i][kkk];
#pragma unroll
      for (int dd = 0; dd < 4; ++dd) *(float4*)vb[dd] = *(const float4*)&vs[kkk + dd][tx * 4];
#pragma unroll
      for (int i = 0; i < 4; ++i) {
#pragma unroll
        for (int j = 0; j < 4; ++j) {
#pragma unroll
          for (int dd = 0; dd < 4; ++dd) o[i][j] += pa[i][dd] * vb[dd][j];
        }
      }
    }
    __syncthreads();
  }
#pragma unroll
  for (int i = 0; i < 4; ++i) {
    float inv = 1.0f / li[i];
    float4 v;
    v.x = o[i][0] * inv; v.y = o[i][1] * inv; v.z = o[i][2] * inv; v.w = o[i][3] * inv;
    *(float4*)(AO + (size_t)(b * nq + q0 + ty * 4 + i) * 1024 + h * 64 + tx * 4) = v;
  }
}

// ---------------- router: logits & noise_logits (N=8 each) -----------
__global__ __launch_bounds__(256) void router_kernel(
    const float* __restrict__ xm, const float* __restrict__ rw,
    const float* __restrict__ rb, const float* __restrict__ nw,
    const float* __restrict__ nb, float* __restrict__ logits,
    float* __restrict__ nlogits) {
  int row = blockIdx.x, t = threadIdx.x;
  const float* x = xm + (size_t)row * 1024;
  float accl[8] = {}, accn[8] = {};
  for (int d = t; d < 1024; d += 256) {
    float xv = x[d];
#pragma unroll
    for (int e = 0; e < 8; ++e) {
      accl[e] += xv * rw[e * 1024 + d];
      accn[e] += xv * nw[e * 1024 + d];
    }
  }
  __shared__ float red[16][4];
  int lane = t & 63, w = t >> 6;
#pragma unroll
  for (int e = 0; e < 8; ++e) {
    float v = accl[e];
    for (int m = 1; m <= 32; m <<= 1) v += __shfl_xor(v, m, 64);
    if (lane == 0) red[e][w] = v;
    float v2 = accn[e];
    for (int m = 1; m <= 32; m <<= 1) v2 += __shfl_xor(v2, m, 64);
    if (lane == 0) red[8 + e][w] = v2;
  }
  __syncthreads();
  if (t < 8)
    logits[row * 8 + t] = red[t][0] + red[t][1] + red[t][2] + red[t][3] + rb[t];
  else if (t < 16)
    nlogits[row * 8 + t - 8] =
        red[t][0] + red[t][1] + red[t][2] + red[t][3] + nb[t - 8];
}

// ---------------- routing: noisy top-2, probs, expert counts ---------
__global__ __launch_bounds__(256) void route_kernel(
    const float* __restrict__ logits, const float* __restrict__ nlogits,
    const float* __restrict__ normals, int* __restrict__ routei,
    float* __restrict__ routep, int* __restrict__ cnt) {
  int bt = blockIdx.x * 256 + threadIdx.x;
  if (bt >= 2048) return;
  float noisy[8];
#pragma unroll
  for (int e = 0; e < 8; ++e) {
    float nl = nlogits[bt * 8 + e];
    float sp = fmaxf(nl, 0.0f) + log1pf(expf(-fabsf(nl)));  // softplus
    noisy[e] = logits[bt * 8 + e] + normals[bt * 8 + e] * sp;
  }
  int i1 = 0; float n1 = noisy[0];
#pragma unroll
  for (int e = 1; e < 8; ++e) if (noisy[e] > n1) { n1 = noisy[e]; i1 = e; }
  int i2 = -1; float n2 = -INFINITY;
#pragma unroll
  for (int e = 0; e < 8; ++e)
    if (e != i1 && noisy[e] > n2) { n2 = noisy[e]; i2 = e; }
  float e2 = expf(n2 - n1);
  float denom = 1.0f + e2;
  routei[bt * 2 + 0] = i1; routei[bt * 2 + 1] = i2;
  routep[bt * 2 + 0] = 1.0f / denom; routep[bt * 2 + 1] = e2 / denom;
  atomicAdd(&cnt[i1], 1);
  atomicAdd(&cnt[i2], 1);
}

__global__ void zero_kernel(int* __restrict__ cnt) {
  if (threadIdx.x < 8) cnt[threadIdx.x] = 0;
}

__global__ void offs_kernel(const int* __restrict__ cnt, int* __restrict__ offs,
                            int* __restrict__ fill) {
  if (threadIdx.x == 0 && blockIdx.x == 0) {
    int o = 0;
    for (int e = 0; e < 8; ++e) { offs[e] = o; o += cnt[e]; fill[e] = 0; }
  }
}

__global__ __launch_bounds__(256) void fill_kernel(
    const int* __restrict__ routei, const float* __restrict__ routep,
    const int* __restrict__ offs, int* __restrict__ fill,
    int* __restrict__ alist, float* __restrict__ aprob) {
  int bt = blockIdx.x * 256 + threadIdx.x;
  if (bt >= 2048) return;
#pragma unroll
  for (int s = 0; s < 2; ++s) {
    int e = routei[bt * 2 + s];
    int pos = offs[e] + atomicAdd(&fill[e], 1);
    alist[pos] = bt;
    aprob[pos] = routep[bt * 2 + s];
  }
}

__global__ __launch_bounds__(256) void copy_kernel(const float* __restrict__ src,
                                                   float* __restrict__ dst) {
  int i = blockIdx.x * 256 + threadIdx.x;
  ((float4*)dst)[i] = ((const float4*)src)[i];
}

__device__ __forceinline__ float gelu_exact_(float x) {
  return 0.5f * x * (1.0f + erff(x * 0.70710678f));
}

// ---------------- expert FFN1: H = gelu(gather(X) @ W1[e] + b1) ------
__global__ __launch_bounds__(256) void ffn1_kernel(
    const float* __restrict__ X, const float* __restrict__ W1,
    const float* __restrict__ B1, float* __restrict__ H,
    const int* __restrict__ alist, const int* __restrict__ cnt,
    const int* __restrict__ offs) {
  const int e = blockIdx.z;
  const int ce = cnt[e];
  const int m0 = blockIdx.y * 128;
  if (m0 >= ce) return;
  const int off = offs[e];
  const int n0 = blockIdx.x * 128;
  const float* W = W1 + (size_t)e * 1024 * 4096;
  __shared__ float As[16][132];
  __shared__ float Bs[16][132];
  const int t = threadIdx.x;
  const int tx = t & 15, ty = t >> 4;
  float acc[8][8] = {};
  const int r = t >> 1, kk = (t & 1) * 8;
  const int arow = alist[off + imin_(m0 + r, ce - 1)];
  const float* asrc = X + (size_t)arow * 1024 + kk;
  const int nn = (t & 15) * 8;
  const float* wsrc = W + (size_t)ty * 4096 + n0 + nn;  // ty = k-row 0..15
  for (int k0 = 0; k0 < 1024; k0 += 16) {
    float4 a0 = *(const float4*)(asrc);
    float4 a1 = *(const float4*)(asrc + 4);
    float4 b0 = *(const float4*)(wsrc);
    float4 b1 = *(const float4*)(wsrc + 4);
    asrc += 16; wsrc += (size_t)16 * 4096;
    As[kk + 0][r] = a0.x; As[kk + 1][r] = a0.y; As[kk + 2][r] = a0.z; As[kk + 3][r] = a0.w;
    As[kk + 4][r] = a1.x; As[kk + 5][r] = a1.y; As[kk + 6][r] = a1.z; As[kk + 7][r] = a1.w;
    *(float4*)&Bs[ty][nn] = b0;
    *(float4*)&Bs[ty][nn + 4] = b1;
    __syncthreads();
#pragma unroll
    for (int k = 0; k < 16; ++k) {
      float a[8], bb[8];
      *(float4*)&a[0]  = *(const float4*)&As[k][ty * 4];
      *(float4*)&a[4]  = *(const float4*)&As[k][64 + ty * 4];
      *(float4*)&bb[0] = *(const float4*)&Bs[k][tx * 4];
      *(float4*)&bb[4] = *(const float4*)&Bs[k][64 + tx * 4];
#pragma unroll
      for (int i = 0; i < 8; ++i) {
#pragma unroll
        for (int j = 0; j < 8; ++j) acc[i][j] += a[i] * bb[j];
      }
    }
    __syncthreads();
  }
  float4 bv0 = *(const float4*)&B1[(size_t)e * 4096 + n0 + tx * 4];
  float4 bv1 = *(const float4*)&B1[(size_t)e * 4096 + n0 + 64 + tx * 4];
  float bb[8] = {bv0.x, bv0.y, bv0.z, bv0.w, bv1.x, bv1.y, bv1.z, bv1.w};
#pragma unroll
  for (int i = 0; i < 8; ++i) {
    int mr = m0 + ((i < 4) ? (ty * 4 + i) : (64 + ty * 4 + i - 4));
    if (mr < ce) {
      float* hrow = H + (size_t)(off + mr) * 4096 + n0;
      float v[8];
#pragma unroll
      for (int j = 0; j < 8; ++j) v[j] = gelu_exact_(acc[i][j] + bb[j]);
      *(float4*)(hrow + tx * 4)      = *(float4*)&v[0];
      *(float4*)(hrow + 64 + tx * 4) = *(float4*)&v[4];
    }
  }
}

// ------- expert FFN2: out[tok] += p * (H @ W2[e] + b2), atomic -------
__global__ __launch_bounds__(256) void ffn2_kernel(
    const float* __restrict__ H, const float* __restrict__ W2,
    const float* __restrict__ B2, float* __restrict__ Out,
    const int* __restrict__ alist, const float* __restrict__ aprob,
    const int* __restrict__ cnt, const int* __restrict__ offs) {
  const int e = blockIdx.z;
  const int ce = cnt[e];
  const int m0 = blockIdx.y * 128;
  if (m0 >= ce) return;
  const int off = offs[e];
  const int n0 = blockIdx.x * 128;
  const float* W = W2 + (size_t)e * 4096 * 1024;
  __shared__ float As[16][132];
  __shared__ float Bs[16][132];
  const int t = threadIdx.x;
  const int tx = t & 15, ty = t >> 4;
  float acc[8][8] = {};
  const int r = t >> 1, kk = (t & 1) * 8;
  const float* asrc = H + (size_t)(off + imin_(m0 + r, ce - 1)) * 4096 + kk;
  const int nn = (t & 15) * 8;
  const float* wsrc = W + (size_t)ty * 1024 + n0 + nn;
  for (int k0 = 0; k0 < 4096; k0 += 16) {
    float4 a0 = *(const float4*)(asrc);
    float4 a1 = *(const float4*)(asrc + 4);
    float4 b0 = *(const float4*)(wsrc);
    float4 b1 = *(const float4*)(wsrc + 4);
    asrc += 16; wsrc += (size_t)16 * 1024;
    As[kk + 0][r] = a0.x; As[kk + 1][r] = a0.y; As[kk + 2][r] = a0.z; As[kk + 3][r] = a0.w;
    As[kk + 4][r] = a1.x; As[kk + 5][r] = a1.y; As[kk + 6][r] = a1.z; As[kk + 7][r] = a1.w;
    *(float4*)&Bs[ty][nn] = b0;
    *(float4*)&Bs[ty][nn + 4] = b1;
    __syncthreads();
#pragma unroll
    for (int k = 0; k < 16; ++k) {
      float a[8], bb[8];
      *(float4*)&a[0]  = *(const float4*)&As[k][ty * 4];
      *(float4*)&a[4]  = *(const float4*)&As[k][64 + ty * 4];
      *(float4*)&bb[0] = *(const float4*)&Bs[k][tx * 4];
      *(float4*)&bb[4] = *(const float4*)&Bs[k][64 + tx * 4];
#pragma unroll
      for (int i = 0; i < 8; ++i) {
#pragma unroll
        for (int j = 0; j < 8; ++j) acc[i][j] += a[i] * bb[j];
      }
    }
    __syncthreads();
  }
  float4 bv0 = *(const float4*)&B2[(size_t)e * 1024 + n0 + tx * 4];
  float4 bv1 = *(const float4*)&B2[(size_t)e * 1024 + n0 + 64 + tx * 4];
  float bb[8] = {bv0.x, bv0.y, bv0.z, bv0.w, bv1.x, bv1.y, bv1.z, bv1.w};
#pragma unroll
  for (int i = 0; i < 8; ++i) {
    int mr = m0 + ((i < 4) ? (ty * 4 + i) : (64 + ty * 4 + i - 4));
    if (mr < ce) {
      int aidx = off + mr;
      int tok = alist[aidx];
      float p = aprob[aidx];
      float* orow = Out + (size_t)tok * 1024 + n0;
#pragma unroll
      for (int j = 0; j < 8; ++j) {
        int col = (j < 4) ? (tx * 4 + j) : (64 + tx * 4 + j - 4);
        atomicAdd(&orow[col], p * (acc[i][j] + bb[j]));
      }
    }
  }
}

// =====================================================================
extern "C" void kernel_launch(void* const* d_in, const int* in_sizes, int n_in,
                              void* d_out, int out_size, void* d_ws, size_t ws_size,
                              hipStream_t stream) {
  (void)in_sizes; (void)n_in; (void)out_size; (void)ws_size;
  const float* q        = (const float*)d_in[0];
  const float* kv       = (const float*)d_in[1];
  const float* ln_cq_g  = (const float*)d_in[2];
  const float* ln_cq_b  = (const float*)d_in[3];
  const float* ln_ckv_g = (const float*)d_in[4];
  const float* ln_ckv_b = (const float*)d_in[5];
  const float* ln_s_g   = (const float*)d_in[6];
  const float* ln_s_b   = (const float*)d_in[7];
  const float* ln_m_g   = (const float*)d_in[8];
  const float* ln_m_b   = (const float*)d_in[9];
  const float* ca_in_w  = (const float*)d_in[10];
  const float* ca_in_b  = (const float*)d_in[11];
  const float* ca_out_w = (const float*)d_in[12];
  const float* ca_out_b = (const float*)d_in[13];
  const float* sa_in_w  = (const float*)d_in[14];
  const float* sa_in_b  = (const float*)d_in[15];
  const float* sa_out_w = (const float*)d_in[16];
  const float* sa_out_b = (const float*)d_in[17];
  const float* moe_rw   = (const float*)d_in[18];
  const float* moe_rb   = (const float*)d_in[19];
  const float* moe_nw   = (const float*)d_in[20];
  const float* moe_nb   = (const float*)d_in[21];
  const float* moe_w1   = (const float*)d_in[22];
  const float* moe_b1   = (const float*)d_in[23];
  const float* moe_w2   = (const float*)d_in[24];
  const float* moe_b2   = (const float*)d_in[25];
  float* out = (float*)d_out;

  // -------- workspace layout (floats). Peak ~110 MB. --------
  float* ws = (float*)d_ws;
  const size_t MEG = 1u << 20;
  float* ao   = ws;               // 2M  attn output (cross, then self)
  float* x1   = ws + 2 * MEG;     // 2M  x after cross residual
  float* xs   = ws + 4 * MEG;     // 2M  LN_s(x1)
  float* x2   = ws + 6 * MEG;     // 2M  x after self residual
  float* xm   = ws + 8 * MEG;     // 2M  LN_m(x2)
  float* misc = ws + 10 * MEG;
  float* normals = misc;                      // 16384
  float* logits  = misc + 16384;              // 16384
  float* nlogits = misc + 32768;              // 16384
  float* routep  = misc + 49152;              // 4096
  float* aprob   = misc + 53248;              // 4096
  int*   routei  = (int*)(misc + 57344);      // 4096
  int*   alist   = (int*)(misc + 61440);      // 4096
  int*   cnt     = (int*)(misc + 65536);      // 8
  int*   offs    = cnt + 8;                   // 8
  int*   fillc   = cnt + 16;                  // 8
  float* RA = ws + 10 * MEG + 131072;         // 16M region, phase-reused
  float* lnkv = RA;               // cross phase
  float* lnq  = RA + 4 * MEG;
  float* qp   = RA + 6 * MEG;
  float* kp   = RA + 8 * MEG;
  float* vp   = RA + 12 * MEG;
  float* sqp  = RA;               // self phase
  float* skp  = RA + 2 * MEG;
  float* svp  = RA + 4 * MEG;
  float* hbuf = RA;               // moe phase: 4096 x 4096 fp32

  dim3 blk(256);

  zero_kernel<<<dim3(1), blk, 0, stream>>>(cnt);
  noise_kernel<<<dim3(64), blk, 0, stream>>>(normals);

  // ---- cross attention ----
  ln_kernel<<<dim3(2048), blk, 0, stream>>>(q, ln_cq_g, ln_cq_b, lnq);
  ln_kernel<<<dim3(4096), blk, 0, stream>>>(kv, ln_ckv_g, ln_ckv_b, lnkv);
  gemm_nt<false><<<dim3(8, 16), blk, 0, stream>>>(lnq, ca_in_w, ca_in_b, nullptr, qp, 2048, 1024, 1024);
  gemm_nt<false><<<dim3(8, 32), blk, 0, stream>>>(lnkv, ca_in_w + MEG, ca_in_b + 1024, nullptr, kp, 4096, 1024, 1024);
  gemm_nt<false><<<dim3(8, 32), blk, 0, stream>>>(lnkv, ca_in_w + 2 * MEG, ca_in_b + 2048, nullptr, vp, 4096, 1024, 1024);
  attn_kernel<<<dim3(32, 16), blk, 0, stream>>>(qp, kp, vp, ao, 1024, 2048);
  gemm_nt<true><<<dim3(8, 16), blk, 0, stream>>>(ao, ca_out_w, ca_out_b, q, x1, 2048, 1024, 1024);

  // ---- self attention ----
  ln_kernel<<<dim3(2048), blk, 0, stream>>>(x1, ln_s_g, ln_s_b, xs);
  gemm_nt<false><<<dim3(8, 16), blk, 0, stream>>>(xs, sa_in_w, sa_in_b, nullptr, sqp, 2048, 1024, 1024);
  gemm_nt<false><<<dim3(8, 16), blk, 0, stream>>>(xs, sa_in_w + MEG, sa_in_b + 1024, nullptr, skp, 2048, 1024, 1024);
  gemm_nt<false><<<dim3(8, 16), blk, 0, stream>>>(xs, sa_in_w + 2 * MEG, sa_in_b + 2048, nullptr, svp, 2048, 1024, 1024);
  attn_kernel<<<dim3(32, 16), blk, 0, stream>>>(sqp, skp, svp, ao, 1024, 1024);
  gemm_nt<true><<<dim3(8, 16), blk, 0, stream>>>(ao, sa_out_w, sa_out_b, x1, x2, 2048, 1024, 1024);

  // ---- MoE ----
  ln_kernel<<<dim3(2048), blk, 0, stream>>>(x2, ln_m_g, ln_m_b, xm);
  router_kernel<<<dim3(2048), blk, 0, stream>>>(xm, moe_rw, moe_rb, moe_nw, moe_nb, logits, nlogits);
  route_kernel<<<dim3(8), blk, 0, stream>>>(logits, nlogits, normals, routei, routep, cnt);
  offs_kernel<<<dim3(1), blk, 0, stream>>>(cnt, offs, fillc);
  fill_kernel<<<dim3(8), blk, 0, stream>>>(routei, routep, offs, fillc, alist, aprob);
  copy_kernel<<<dim3(2048), blk, 0, stream>>>(x2, out);  // residual base
  ffn1_kernel<<<dim3(32, 16, 8), blk, 0, stream>>>(xm, moe_w1, moe_b1, hbuf, alist, cnt, offs);
  ffn2_kernel<<<dim3(8, 16, 8), blk, 0, stream>>>(hbuf, moe_w2, moe_b2, out, alist, aprob, cnt, offs);
}

// Round 2
// 2510.151 us; speedup vs baseline: 1.4792x; 1.4792x over previous
//
#include <hip/hip_runtime.h>
#include <cstdint>
#include <cstddef>

// =====================================================================
// LENet block: x = MHA(LN(q), LN(kv)) + q ; x = MHA(LN(x),LN(x)) + x ;
//              x = NoisyTop2MoE(LN(x)) + x
// Round 2: x-path (LN/projections/attention/router) stays fp32 (routing
// needs ~1e-5 accuracy — bf16 there would flip top-2 picks). Expert FFNs
// moved to bf16 MFMA (16x16x32) — they only affect the 0.1075-threshold
// output, and round-1 slack was 7x.
// =====================================================================
#define JAX_THREEFRY_PARTITIONABLE 1

typedef unsigned short u16;
typedef __attribute__((ext_vector_type(8))) short bf16x8;   // 8 bf16 = 4 VGPR
typedef __attribute__((ext_vector_type(4))) float f32x4;

__device__ __forceinline__ int imin_(int a, int b) { return a < b ? a : b; }

__device__ __forceinline__ u16 f2bf_(float f) {  // RNE float->bf16
  unsigned u = __float_as_uint(f);
  return (u16)((u + 0x7fffu + ((u >> 16) & 1u)) >> 16);
}

// ---------------- threefry2x32 (JAX-exact, 20 rounds) ----------------
__device__ __forceinline__ unsigned rotl32_(unsigned v, int d) {
  return (v << d) | (v >> (32 - d));
}

__device__ __forceinline__ void threefry2x32_(unsigned k0, unsigned k1,
                                              unsigned x0, unsigned x1,
                                              unsigned& o0, unsigned& o1) {
  unsigned ks2 = k0 ^ k1 ^ 0x1BD11BDAu;
  x0 += k0; x1 += k1;
#define TF_R(rot) { x0 += x1; x1 = rotl32_(x1, rot); x1 ^= x0; }
  TF_R(13) TF_R(15) TF_R(26) TF_R(6)
  x0 += k1;  x1 += ks2 + 1u;
  TF_R(17) TF_R(29) TF_R(16) TF_R(24)
  x0 += ks2; x1 += k0 + 2u;
  TF_R(13) TF_R(15) TF_R(26) TF_R(6)
  x0 += k0;  x1 += k1 + 3u;
  TF_R(17) TF_R(29) TF_R(16) TF_R(24)
  x0 += k1;  x1 += ks2 + 4u;
  TF_R(13) TF_R(15) TF_R(26) TF_R(6)
  x0 += ks2; x1 += k0 + 5u;
#undef TF_R
  o0 = x0; o1 = x1;
}

// XLA ErfInv32 (Giles polynomial) — matches lax.erf_inv on f32.
__device__ float erfinv_f32_(float x) {
  float w = -log1pf(-x * x);
  float p;
  if (w < 5.0f) {
    w -= 2.5f;
    p = 2.81022636e-08f;
    p = fmaf(p, w, 3.43273939e-07f);
    p = fmaf(p, w, -3.5233877e-06f);
    p = fmaf(p, w, -4.39150654e-06f);
    p = fmaf(p, w, 0.00021858087f);
    p = fmaf(p, w, -0.00125372503f);
    p = fmaf(p, w, -0.00417768164f);
    p = fmaf(p, w, 0.246640727f);
    p = fmaf(p, w, 1.50140941f);
  } else {
    w = sqrtf(w) - 3.0f;
    p = -0.000200214257f;
    p = fmaf(p, w, 0.000100950558f);
    p = fmaf(p, w, 0.00134934322f);
    p = fmaf(p, w, -0.00367342844f);
    p = fmaf(p, w, 0.00573950773f);
    p = fmaf(p, w, -0.0076224613f);
    p = fmaf(p, w, 0.00943887047f);
    p = fmaf(p, w, 1.00167406f);
    p = fmaf(p, w, 2.83297682f);
  }
  return p * x;
}

__device__ float bits_to_normal_(unsigned b) {
  const float lo = -0.99999994f;  // nextafter(-1, 0) in f32
  float f = __uint_as_float((b >> 9) | 0x3f800000u) - 1.0f;  // [0,1)
  float u = fmaxf(lo, f * 2.0f + lo);
  return 1.41421356237f * erfinv_f32_(u);
}

// normals for logits shape (2,1024,8) -> 16384 elems, key = (0,42)
__global__ __launch_bounds__(256) void noise_kernel(float* __restrict__ normals) {
  int i = blockIdx.x * 256 + threadIdx.x;
#if JAX_THREEFRY_PARTITIONABLE
  if (i < 16384) {
    unsigned o0, o1;
    threefry2x32_(0u, 42u, 0u, (unsigned)i, o0, o1);
    normals[i] = bits_to_normal_(o0 ^ o1);
  }
#else
  if (i < 8192) {
    unsigned o0, o1;
    threefry2x32_(0u, 42u, (unsigned)i, (unsigned)(i + 8192), o0, o1);
    normals[i] = bits_to_normal_(o0);
    normals[i + 8192] = bits_to_normal_(o1);
  }
#endif
}

// ---------------- block reduce (256 threads, wave64) -----------------
__device__ float block_reduce_sum_(float v) {
  for (int m = 1; m <= 32; m <<= 1) v += __shfl_xor(v, m, 64);
  __shared__ float red[4];
  int lane = threadIdx.x & 63, w = threadIdx.x >> 6;
  if (lane == 0) red[w] = v;
  __syncthreads();
  v = red[0] + red[1] + red[2] + red[3];
  __syncthreads();
  return v;
}

// ---------------- LayerNorm over last dim (1024) ---------------------
__global__ __launch_bounds__(256) void ln_kernel(
    const float* __restrict__ X, const float* __restrict__ g,
    const float* __restrict__ bta, float* __restrict__ Y) {
  int row = blockIdx.x;
  int t = threadIdx.x;
  const float4* xr = (const float4*)(X + (size_t)row * 1024);
  float4 v = xr[t];
  float s = v.x + v.y + v.z + v.w;
  s = block_reduce_sum_(s);
  float mean = s * (1.0f / 1024.0f);
  float dx = v.x - mean, dy = v.y - mean, dz = v.z - mean, dw = v.w - mean;
  float sq = dx * dx + dy * dy + dz * dz + dw * dw;
  sq = block_reduce_sum_(sq);
  float rstd = 1.0f / sqrtf(sq * (1.0f / 1024.0f) + 1e-5f);
  float4 gv = ((const float4*)g)[t];
  float4 bv = ((const float4*)bta)[t];
  float4 y;
  y.x = dx * rstd * gv.x + bv.x;
  y.y = dy * rstd * gv.y + bv.y;
  y.z = dz * rstd * gv.z + bv.z;
  y.w = dw * rstd * gv.w + bv.w;
  ((float4*)(Y + (size_t)row * 1024))[t] = y;
}

// ---------------- fp32 tiled GEMM: C = A(MxK) @ W(NxK)^T + bias ------
template<bool RESID>
__global__ __launch_bounds__(256) void gemm_nt(
    const float* __restrict__ A, const float* __restrict__ W,
    const float* __restrict__ bias, const float* __restrict__ resid,
    float* __restrict__ C, int M, int N, int K) {
  __shared__ float As[16][132];
  __shared__ float Bs[16][132];
  const int t = threadIdx.x;
  const int tx = t & 15, ty = t >> 4;
  const int n0 = blockIdx.x * 128, m0 = blockIdx.y * 128;
  float acc[8][8] = {};
  const int r = t >> 1, kk = (t & 1) * 8;
  const float* asrc = A + (size_t)(m0 + r) * K + kk;
  const float* wsrc = W + (size_t)(n0 + r) * K + kk;
  for (int k0 = 0; k0 < K; k0 += 16) {
    float4 a0 = *(const float4*)(asrc);
    float4 a1 = *(const float4*)(asrc + 4);
    float4 b0 = *(const float4*)(wsrc);
    float4 b1 = *(const float4*)(wsrc + 4);
    asrc += 16; wsrc += 16;
    As[kk + 0][r] = a0.x; As[kk + 1][r] = a0.y; As[kk + 2][r] = a0.z; As[kk + 3][r] = a0.w;
    As[kk + 4][r] = a1.x; As[kk + 5][r] = a1.y; As[kk + 6][r] = a1.z; As[kk + 7][r] = a1.w;
    Bs[kk + 0][r] = b0.x; Bs[kk + 1][r] = b0.y; Bs[kk + 2][r] = b0.z; Bs[kk + 3][r] = b0.w;
    Bs[kk + 4][r] = b1.x; Bs[kk + 5][r] = b1.y; Bs[kk + 6][r] = b1.z; Bs[kk + 7][r] = b1.w;
    __syncthreads();
#pragma unroll
    for (int k = 0; k < 16; ++k) {
      float a[8], bb[8];
      *(float4*)&a[0]  = *(const float4*)&As[k][ty * 4];
      *(float4*)&a[4]  = *(const float4*)&As[k][64 + ty * 4];
      *(float4*)&bb[0] = *(const float4*)&Bs[k][tx * 4];
      *(float4*)&bb[4] = *(const float4*)&Bs[k][64 + tx * 4];
#pragma unroll
      for (int i = 0; i < 8; ++i) {
#pragma unroll
        for (int j = 0; j < 8; ++j) acc[i][j] += a[i] * bb[j];
      }
    }
    __syncthreads();
  }
  float4 bs0 = *(const float4*)&bias[n0 + tx * 4];
  float4 bs1 = *(const float4*)&bias[n0 + 64 + tx * 4];
  float bb[8] = {bs0.x, bs0.y, bs0.z, bs0.w, bs1.x, bs1.y, bs1.z, bs1.w};
#pragma unroll
  for (int i = 0; i < 8; ++i) {
    int m = m0 + ((i < 4) ? (ty * 4 + i) : (64 + ty * 4 + i - 4));
    float* crow = C + (size_t)m * N + n0;
    float v[8];
#pragma unroll
    for (int j = 0; j < 8; ++j) v[j] = acc[i][j] + bb[j];
    if (RESID) {
      const float* rrow = resid + (size_t)m * N + n0;
      float4 r0 = *(const float4*)(rrow + tx * 4);
      float4 r1 = *(const float4*)(rrow + 64 + tx * 4);
      v[0] += r0.x; v[1] += r0.y; v[2] += r0.z; v[3] += r0.w;
      v[4] += r1.x; v[5] += r1.y; v[6] += r1.z; v[7] += r1.w;
    }
    *(float4*)(crow + tx * 4)      = *(float4*)&v[0];
    *(float4*)(crow + 64 + tx * 4) = *(float4*)&v[4];
  }
}

// ---------------- flash attention, fp32, DH=64 -----------------------
__global__ __launch_bounds__(256) void attn_kernel(
    const float* __restrict__ QP, const float* __restrict__ KP,
    const float* __restrict__ VP, float* __restrict__ AO,
    int nq, int nkv) {
  __shared__ float qs[64][68];
  __shared__ float kst[64][68];
  __shared__ float vs[64][68];
  __shared__ float ps[64][68];
  const int t = threadIdx.x;
  const int tx = t & 15, ty = t >> 4;
  const int bh = blockIdx.x;
  const int b = bh >> 4, h = bh & 15;
  const int q0 = blockIdx.y * 64;
  {
    int r = t >> 2, c = (t & 3) * 16;
    const float* src = QP + (size_t)(b * nq + q0 + r) * 1024 + h * 64 + c;
#pragma unroll
    for (int j = 0; j < 4; ++j) {
      float4 v = *(const float4*)(src + 4 * j);
      v.x *= 0.125f; v.y *= 0.125f; v.z *= 0.125f; v.w *= 0.125f;
      *(float4*)&qs[r][c + 4 * j] = v;
    }
  }
  float o[4][4] = {};
  float mi[4] = {-INFINITY, -INFINITY, -INFINITY, -INFINITY};
  float li[4] = {};
  for (int kv0 = 0; kv0 < nkv; kv0 += 64) {
    {
      int r = t >> 2, c = (t & 3) * 16;
      const float* ksrc = KP + (size_t)(b * nkv + kv0 + r) * 1024 + h * 64 + c;
      const float* vsrc = VP + (size_t)(b * nkv + kv0 + r) * 1024 + h * 64 + c;
#pragma unroll
      for (int j = 0; j < 4; ++j) {
        float4 kvv = *(const float4*)(ksrc + 4 * j);
        kst[c + 4 * j + 0][r] = kvv.x;
        kst[c + 4 * j + 1][r] = kvv.y;
        kst[c + 4 * j + 2][r] = kvv.z;
        kst[c + 4 * j + 3][r] = kvv.w;
        *(float4*)&vs[r][c + 4 * j] = *(const float4*)(vsrc + 4 * j);
      }
    }
    __syncthreads();
    float s[4][4] = {};
#pragma unroll
    for (int d = 0; d < 64; d += 4) {
      float qa[4][4], kb[4][4];
#pragma unroll
      for (int i = 0; i < 4; ++i) *(float4*)qa[i] = *(const float4*)&qs[ty * 4 + i][d];
#pragma unroll
      for (int dd = 0; dd < 4; ++dd) *(float4*)kb[dd] = *(const float4*)&kst[d + dd][tx * 4];
#pragma unroll
      for (int i = 0; i < 4; ++i) {
#pragma unroll
        for (int j = 0; j < 4; ++j) {
#pragma unroll
          for (int dd = 0; dd < 4; ++dd) s[i][j] += qa[i][dd] * kb[dd][j];
        }
      }
    }
    float al[4];
#pragma unroll
    for (int i = 0; i < 4; ++i) {
      float rm = fmaxf(fmaxf(s[i][0], s[i][1]), fmaxf(s[i][2], s[i][3]));
      rm = fmaxf(rm, __shfl_xor(rm, 1, 64));
      rm = fmaxf(rm, __shfl_xor(rm, 2, 64));
      rm = fmaxf(rm, __shfl_xor(rm, 4, 64));
      rm = fmaxf(rm, __shfl_xor(rm, 8, 64));
      float mnew = fmaxf(mi[i], rm);
      al[i] = expf(mi[i] - mnew);
      float rs = 0.0f;
#pragma unroll
      for (int j = 0; j < 4; ++j) { s[i][j] = expf(s[i][j] - mnew); rs += s[i][j]; }
      rs += __shfl_xor(rs, 1, 64);
      rs += __shfl_xor(rs, 2, 64);
      rs += __shfl_xor(rs, 4, 64);
      rs += __shfl_xor(rs, 8, 64);
      li[i] = li[i] * al[i] + rs;
      mi[i] = mnew;
      *(float4*)&ps[ty * 4 + i][tx * 4] = *(float4*)s[i];
    }
#pragma unroll
    for (int i = 0; i < 4; ++i) {
#pragma unroll
      for (int j = 0; j < 4; ++j) o[i][j] *= al[i];
    }
    __syncthreads();
#pragma unroll
    for (int kkk = 0; kkk < 64; kkk += 4) {
      float pa[4][4], vb[4][4];
#pragma unroll
      for (int i = 0; i < 4; ++i) *(float4*)pa[i] = *(const float4*)&ps[ty * 4 + i][kkk];
#pragma unroll
      for (int dd = 0; dd < 4; ++dd) *(float4*)vb[dd] = *(const float4*)&vs[kkk + dd][tx * 4];
#pragma unroll
      for (int i = 0; i < 4; ++i) {
#pragma unroll
        for (int j = 0; j < 4; ++j) {
#pragma unroll
          for (int dd = 0; dd < 4; ++dd) o[i][j] += pa[i][dd] * vb[dd][j];
        }
      }
    }
    __syncthreads();
  }
#pragma unroll
  for (int i = 0; i < 4; ++i) {
    float inv = 1.0f / li[i];
    float4 v;
    v.x = o[i][0] * inv; v.y = o[i][1] * inv; v.z = o[i][2] * inv; v.w = o[i][3] * inv;
    *(float4*)(AO + (size_t)(b * nq + q0 + ty * 4 + i) * 1024 + h * 64 + tx * 4) = v;
  }
}

// ---------------- router: logits & noise_logits (N=8 each) -----------
__global__ __launch_bounds__(256) void router_kernel(
    const float* __restrict__ xm, const float* __restrict__ rw,
    const float* __restrict__ rb, const float* __restrict__ nw,
    const float* __restrict__ nb, float* __restrict__ logits,
    float* __restrict__ nlogits) {
  int row = blockIdx.x, t = threadIdx.x;
  const float* x = xm + (size_t)row * 1024;
  float accl[8] = {}, accn[8] = {};
  for (int d = t; d < 1024; d += 256) {
    float xv = x[d];
#pragma unroll
    for (int e = 0; e < 8; ++e) {
      accl[e] += xv * rw[e * 1024 + d];
      accn[e] += xv * nw[e * 1024 + d];
    }
  }
  __shared__ float red[16][4];
  int lane = t & 63, w = t >> 6;
#pragma unroll
  for (int e = 0; e < 8; ++e) {
    float v = accl[e];
    for (int m = 1; m <= 32; m <<= 1) v += __shfl_xor(v, m, 64);
    if (lane == 0) red[e][w] = v;
    float v2 = accn[e];
    for (int m = 1; m <= 32; m <<= 1) v2 += __shfl_xor(v2, m, 64);
    if (lane == 0) red[8 + e][w] = v2;
  }
  __syncthreads();
  if (t < 8)
    logits[row * 8 + t] = red[t][0] + red[t][1] + red[t][2] + red[t][3] + rb[t];
  else if (t < 16)
    nlogits[row * 8 + t - 8] =
        red[t][0] + red[t][1] + red[t][2] + red[t][3] + nb[t - 8];
}

// ---------------- routing: noisy top-2, probs, expert counts ---------
__global__ __launch_bounds__(256) void route_kernel(
    const float* __restrict__ logits, const float* __restrict__ nlogits,
    const float* __restrict__ normals, int* __restrict__ routei,
    float* __restrict__ routep, int* __restrict__ cnt) {
  int bt = blockIdx.x * 256 + threadIdx.x;
  if (bt >= 2048) return;
  float noisy[8];
#pragma unroll
  for (int e = 0; e < 8; ++e) {
    float nl = nlogits[bt * 8 + e];
    float sp = fmaxf(nl, 0.0f) + log1pf(expf(-fabsf(nl)));  // softplus
    noisy[e] = logits[bt * 8 + e] + normals[bt * 8 + e] * sp;
  }
  int i1 = 0; float n1 = noisy[0];
#pragma unroll
  for (int e = 1; e < 8; ++e) if (noisy[e] > n1) { n1 = noisy[e]; i1 = e; }
  int i2 = -1; float n2 = -INFINITY;
#pragma unroll
  for (int e = 0; e < 8; ++e)
    if (e != i1 && noisy[e] > n2) { n2 = noisy[e]; i2 = e; }
  float e2 = expf(n2 - n1);
  float denom = 1.0f + e2;
  routei[bt * 2 + 0] = i1; routei[bt * 2 + 1] = i2;
  routep[bt * 2 + 0] = 1.0f / denom; routep[bt * 2 + 1] = e2 / denom;
  atomicAdd(&cnt[i1], 1);
  atomicAdd(&cnt[i2], 1);
}

__global__ void zero_kernel(int* __restrict__ cnt) {
  if (threadIdx.x < 8) cnt[threadIdx.x] = 0;
}

__global__ void offs_kernel(const int* __restrict__ cnt, int* __restrict__ offs,
                            int* __restrict__ fill) {
  if (threadIdx.x == 0 && blockIdx.x == 0) {
    int o = 0;
    for (int e = 0; e < 8; ++e) { offs[e] = o; o += cnt[e]; fill[e] = 0; }
  }
}

__global__ __launch_bounds__(256) void fill_kernel(
    const int* __restrict__ routei, const float* __restrict__ routep,
    const int* __restrict__ offs, int* __restrict__ fill,
    int* __restrict__ alist, float* __restrict__ aprob) {
  int bt = blockIdx.x * 256 + threadIdx.x;
  if (bt >= 2048) return;
#pragma unroll
  for (int s = 0; s < 2; ++s) {
    int e = routei[bt * 2 + s];
    int pos = offs[e] + atomicAdd(&fill[e], 1);
    alist[pos] = bt;
    aprob[pos] = routep[bt * 2 + s];
  }
}

__global__ __launch_bounds__(256) void copy_kernel(const float* __restrict__ src,
                                                   float* __restrict__ dst) {
  int i = blockIdx.x * 256 + threadIdx.x;
  ((float4*)dst)[i] = ((const float4*)src)[i];
}

// fp32 -> bf16 convert, 2M elems
__global__ __launch_bounds__(256) void f2bf_kernel(const float* __restrict__ src,
                                                   u16* __restrict__ dst) {
  int i = (blockIdx.x * 256 + threadIdx.x) * 4;
  float4 v = *(const float4*)(src + i);
  ushort4 o;
  o.x = f2bf_(v.x); o.y = f2bf_(v.y); o.z = f2bf_(v.z); o.w = f2bf_(v.w);
  *(ushort4*)(dst + i) = o;
}

__device__ __forceinline__ float gelu_exact_(float x) {
  return 0.5f * x * (1.0f + erff(x * 0.70710678f));
}

// ===================== bf16 MFMA expert GEMMs ========================
// 128x128 tile, BK=32, 4 waves, each wave = 4x4 grid of 16x16x32 MFMA.
// A (tokens/H): bf16 in global, k-contiguous rows -> LDS [128][32].
// B (weight):   fp32 [K][N]-major in global -> convert+transpose to
//               LDS Bs[n][k] (thread t: n=t>>1, 16 k's -> b128 writes,
//               conflict-free sequential sweep).
// Frag layouts (guide-verified m89/m91): A[m=lane&15][k=quad*8+j],
// B[n=lane&15][k=quad*8+j], C/D col=lane&15 row=quad*4+reg.

__global__ __launch_bounds__(256) void ffn1_mfma(
    const u16* __restrict__ Xb, const float* __restrict__ W1,
    const float* __restrict__ B1, u16* __restrict__ H,
    const int* __restrict__ alist, const int* __restrict__ cnt,
    const int* __restrict__ offs) {
  const int e = blockIdx.z;
  const int ce = cnt[e];
  const int m0 = blockIdx.y * 128;
  if (m0 >= ce) return;
  const int off = offs[e];
  const int n0 = blockIdx.x * 128;
  const float* W = W1 + (size_t)e * (1024 * 4096);
  __shared__ __align__(16) u16 As[128 * 32];
  __shared__ __align__(16) u16 Bs[128 * 32];
  const int t = threadIdx.x;
  const int lane = t & 63, wv = t >> 6;
  const int wm = (wv & 1) * 64, wn = (wv >> 1) * 64;
  const int col = lane & 15, quad = lane >> 4;
  f32x4 acc[4][4] = {};
  const int ar = t >> 1, ak = (t & 1) * 16;
  const int arow = alist[off + imin_(m0 + ar, ce - 1)];
  const u16* asrc = Xb + (size_t)arow * 1024 + ak;
  const int bn = t >> 1, bk = (t & 1) * 16;
  const float* wsrc = W + (size_t)bk * 4096 + n0 + bn;
  for (int k0 = 0; k0 < 1024; k0 += 32) {
    uint4 a0 = *(const uint4*)(asrc);
    uint4 a1 = *(const uint4*)(asrc + 8);
    u16 ub[16];
#pragma unroll
    for (int kk = 0; kk < 16; ++kk) ub[kk] = f2bf_(wsrc[(size_t)kk * 4096]);
    asrc += 32;
    wsrc += (size_t)32 * 4096;
    *(uint4*)&As[ar * 32 + ak] = a0;
    *(uint4*)&As[ar * 32 + ak + 8] = a1;
    *(uint4*)&Bs[bn * 32 + bk] = *(uint4*)&ub[0];
    *(uint4*)&Bs[bn * 32 + bk + 8] = *(uint4*)&ub[8];
    __syncthreads();
    bf16x8 af[4], bf[4];
#pragma unroll
    for (int i = 0; i < 4; ++i)
      af[i] = *(const bf16x8*)&As[(wm + i * 16 + col) * 32 + quad * 8];
#pragma unroll
    for (int j = 0; j < 4; ++j)
      bf[j] = *(const bf16x8*)&Bs[(wn + j * 16 + col) * 32 + quad * 8];
#pragma unroll
    for (int i = 0; i < 4; ++i)
#pragma unroll
      for (int j = 0; j < 4; ++j)
        acc[i][j] = __builtin_amdgcn_mfma_f32_16x16x32_bf16(af[i], bf[j], acc[i][j], 0, 0, 0);
    __syncthreads();
  }
#pragma unroll
  for (int j = 0; j < 4; ++j) {
    int n = n0 + wn + j * 16 + col;
    float bv = B1[(size_t)e * 4096 + n];
#pragma unroll
    for (int i = 0; i < 4; ++i) {
#pragma unroll
      for (int r = 0; r < 4; ++r) {
        int m = m0 + wm + i * 16 + quad * 4 + r;
        if (m < ce) {
          float v = gelu_exact_(acc[i][j][r] + bv);
          H[(size_t)(off + m) * 4096 + n] = f2bf_(v);
        }
      }
    }
  }
}

__global__ __launch_bounds__(256) void ffn2_mfma(
    const u16* __restrict__ H, const float* __restrict__ W2,
    const float* __restrict__ B2, float* __restrict__ Out,
    const int* __restrict__ alist, const float* __restrict__ aprob,
    const int* __restrict__ cnt, const int* __restrict__ offs) {
  const int e = blockIdx.z;
  const int ce = cnt[e];
  const int m0 = blockIdx.y * 128;
  if (m0 >= ce) return;
  const int off = offs[e];
  const int n0 = blockIdx.x * 128;
  const float* W = W2 + (size_t)e * (4096 * 1024);
  __shared__ __align__(16) u16 As[128 * 32];
  __shared__ __align__(16) u16 Bs[128 * 32];
  const int t = threadIdx.x;
  const int lane = t & 63, wv = t >> 6;
  const int wm = (wv & 1) * 64, wn = (wv >> 1) * 64;
  const int col = lane & 15, quad = lane >> 4;
  f32x4 acc[4][4] = {};
  const int ar = t >> 1, ak = (t & 1) * 16;
  const u16* asrc = H + (size_t)(off + imin_(m0 + ar, ce - 1)) * 4096 + ak;
  const int bn = t >> 1, bk = (t & 1) * 16;
  const float* wsrc = W + (size_t)bk * 1024 + n0 + bn;
  for (int k0 = 0; k0 < 4096; k0 += 32) {
    uint4 a0 = *(const uint4*)(asrc);
    uint4 a1 = *(const uint4*)(asrc + 8);
    u16 ub[16];
#pragma unroll
    for (int kk = 0; kk < 16; ++kk) ub[kk] = f2bf_(wsrc[(size_t)kk * 1024]);
    asrc += 32;
    wsrc += (size_t)32 * 1024;
    *(uint4*)&As[ar * 32 + ak] = a0;
    *(uint4*)&As[ar * 32 + ak + 8] = a1;
    *(uint4*)&Bs[bn * 32 + bk] = *(uint4*)&ub[0];
    *(uint4*)&Bs[bn * 32 + bk + 8] = *(uint4*)&ub[8];
    __syncthreads();
    bf16x8 af[4], bf[4];
#pragma unroll
    for (int i = 0; i < 4; ++i)
      af[i] = *(const bf16x8*)&As[(wm + i * 16 + col) * 32 + quad * 8];
#pragma unroll
    for (int j = 0; j < 4; ++j)
      bf[j] = *(const bf16x8*)&Bs[(wn + j * 16 + col) * 32 + quad * 8];
#pragma unroll
    for (int i = 0; i < 4; ++i)
#pragma unroll
      for (int j = 0; j < 4; ++j)
        acc[i][j] = __builtin_amdgcn_mfma_f32_16x16x32_bf16(af[i], bf[j], acc[i][j], 0, 0, 0);
    __syncthreads();
  }
  float bv[4];
#pragma unroll
  for (int j = 0; j < 4; ++j) bv[j] = B2[(size_t)e * 1024 + n0 + wn + j * 16 + col];
#pragma unroll
  for (int i = 0; i < 4; ++i) {
#pragma unroll
    for (int r = 0; r < 4; ++r) {
      int m = m0 + wm + i * 16 + quad * 4 + r;
      if (m < ce) {
        int aidx = off + m;
        int tok = alist[aidx];
        float p = aprob[aidx];
        float* orow = Out + (size_t)tok * 1024;
#pragma unroll
        for (int j = 0; j < 4; ++j) {
          int n = n0 + wn + j * 16 + col;
          atomicAdd(&orow[n], p * (acc[i][j][r] + bv[j]));
        }
      }
    }
  }
}

// =====================================================================
extern "C" void kernel_launch(void* const* d_in, const int* in_sizes, int n_in,
                              void* d_out, int out_size, void* d_ws, size_t ws_size,
                              hipStream_t stream) {
  (void)in_sizes; (void)n_in; (void)out_size; (void)ws_size;
  const float* q        = (const float*)d_in[0];
  const float* kv       = (const float*)d_in[1];
  const float* ln_cq_g  = (const float*)d_in[2];
  const float* ln_cq_b  = (const float*)d_in[3];
  const float* ln_ckv_g = (const float*)d_in[4];
  const float* ln_ckv_b = (const float*)d_in[5];
  const float* ln_s_g   = (const float*)d_in[6];
  const float* ln_s_b   = (const float*)d_in[7];
  const float* ln_m_g   = (const float*)d_in[8];
  const float* ln_m_b   = (const float*)d_in[9];
  const float* ca_in_w  = (const float*)d_in[10];
  const float* ca_in_b  = (const float*)d_in[11];
  const float* ca_out_w = (const float*)d_in[12];
  const float* ca_out_b = (const float*)d_in[13];
  const float* sa_in_w  = (const float*)d_in[14];
  const float* sa_in_b  = (const float*)d_in[15];
  const float* sa_out_w = (const float*)d_in[16];
  const float* sa_out_b = (const float*)d_in[17];
  const float* moe_rw   = (const float*)d_in[18];
  const float* moe_rb   = (const float*)d_in[19];
  const float* moe_nw   = (const float*)d_in[20];
  const float* moe_nb   = (const float*)d_in[21];
  const float* moe_w1   = (const float*)d_in[22];
  const float* moe_b1   = (const float*)d_in[23];
  const float* moe_w2   = (const float*)d_in[24];
  const float* moe_b2   = (const float*)d_in[25];
  float* out = (float*)d_out;

  float* ws = (float*)d_ws;
  const size_t MEG = 1u << 20;
  float* ao   = ws;               // 2M  attn output (cross, then self)
  float* x1   = ws + 2 * MEG;     // 2M  x after cross residual
  float* xs   = ws + 4 * MEG;     // 2M  LN_s(x1)
  float* x2   = ws + 6 * MEG;     // 2M  x after self residual
  float* xm   = ws + 8 * MEG;     // 2M  LN_m(x2)
  float* misc = ws + 10 * MEG;
  float* normals = misc;                      // 16384
  float* logits  = misc + 16384;              // 16384
  float* nlogits = misc + 32768;              // 16384
  float* routep  = misc + 49152;              // 4096
  float* aprob   = misc + 53248;              // 4096
  int*   routei  = (int*)(misc + 57344);      // 4096
  int*   alist   = (int*)(misc + 61440);      // 4096
  int*   cnt     = (int*)(misc + 65536);      // 8
  int*   offs    = cnt + 8;                   // 8
  int*   fillc   = cnt + 16;                  // 8
  float* RA = ws + 10 * MEG + 131072;         // 16M-float region, phase-reused
  float* lnkv = RA;               // cross phase
  float* lnq  = RA + 4 * MEG;
  float* qp   = RA + 6 * MEG;
  float* kp   = RA + 8 * MEG;
  float* vp   = RA + 12 * MEG;
  float* sqp  = RA;               // self phase
  float* skp  = RA + 2 * MEG;
  float* svp  = RA + 4 * MEG;
  u16*   xb   = (u16*)RA;                 // moe phase: 2M bf16 (4 MB)
  u16*   hb   = (u16*)(RA + 1 * MEG);     // moe phase: 4096x4096 bf16 (32 MB)

  dim3 blk(256);

  zero_kernel<<<dim3(1), blk, 0, stream>>>(cnt);
  noise_kernel<<<dim3(64), blk, 0, stream>>>(normals);

  // ---- cross attention ----
  ln_kernel<<<dim3(2048), blk, 0, stream>>>(q, ln_cq_g, ln_cq_b, lnq);
  ln_kernel<<<dim3(4096), blk, 0, stream>>>(kv, ln_ckv_g, ln_ckv_b, lnkv);
  gemm_nt<false><<<dim3(8, 16), blk, 0, stream>>>(lnq, ca_in_w, ca_in_b, nullptr, qp, 2048, 1024, 1024);
  gemm_nt<false><<<dim3(8, 32), blk, 0, stream>>>(lnkv, ca_in_w + MEG, ca_in_b + 1024, nullptr, kp, 4096, 1024, 1024);
  gemm_nt<false><<<dim3(8, 32), blk, 0, stream>>>(lnkv, ca_in_w + 2 * MEG, ca_in_b + 2048, nullptr, vp, 4096, 1024, 1024);
  attn_kernel<<<dim3(32, 16), blk, 0, stream>>>(qp, kp, vp, ao, 1024, 2048);
  gemm_nt<true><<<dim3(8, 16), blk, 0, stream>>>(ao, ca_out_w, ca_out_b, q, x1, 2048, 1024, 1024);

  // ---- self attention ----
  ln_kernel<<<dim3(2048), blk, 0, stream>>>(x1, ln_s_g, ln_s_b, xs);
  gemm_nt<false><<<dim3(8, 16), blk, 0, stream>>>(xs, sa_in_w, sa_in_b, nullptr, sqp, 2048, 1024, 1024);
  gemm_nt<false><<<dim3(8, 16), blk, 0, stream>>>(xs, sa_in_w + MEG, sa_in_b + 1024, nullptr, skp, 2048, 1024, 1024);
  gemm_nt<false><<<dim3(8, 16), blk, 0, stream>>>(xs, sa_in_w + 2 * MEG, sa_in_b + 2048, nullptr, svp, 2048, 1024, 1024);
  attn_kernel<<<dim3(32, 16), blk, 0, stream>>>(sqp, skp, svp, ao, 1024, 1024);
  gemm_nt<true><<<dim3(8, 16), blk, 0, stream>>>(ao, sa_out_w, sa_out_b, x1, x2, 2048, 1024, 1024);

  // ---- MoE ----
  ln_kernel<<<dim3(2048), blk, 0, stream>>>(x2, ln_m_g, ln_m_b, xm);
  f2bf_kernel<<<dim3(2048), blk, 0, stream>>>(xm, xb);
  router_kernel<<<dim3(2048), blk, 0, stream>>>(xm, moe_rw, moe_rb, moe_nw, moe_nb, logits, nlogits);
  route_kernel<<<dim3(8), blk, 0, stream>>>(logits, nlogits, normals, routei, routep, cnt);
  offs_kernel<<<dim3(1), blk, 0, stream>>>(cnt, offs, fillc);
  fill_kernel<<<dim3(8), blk, 0, stream>>>(routei, routep, offs, fillc, alist, aprob);
  copy_kernel<<<dim3(2048), blk, 0, stream>>>(x2, out);  // residual base
  ffn1_mfma<<<dim3(32, 16, 8), blk, 0, stream>>>(xb, moe_w1, moe_b1, hb, alist, cnt, offs);
  ffn2_mfma<<<dim3(8, 16, 8), blk, 0, stream>>>(hb, moe_w2, moe_b2, out, alist, aprob, cnt, offs);
}

// Round 3
// 1813.901 us; speedup vs baseline: 2.0470x; 1.3838x over previous
//
#include <hip/hip_runtime.h>
#include <cstdint>
#include <cstddef>

// =====================================================================
// LENet block: x = MHA(LN(q), LN(kv)) + q ; x = MHA(LN(x),LN(x)) + x ;
//              x = NoisyTop2MoE(LN(x)) + x
// Round 3: projections moved from fp32 VALU to split-bf16 (bf16x3) MFMA:
//   C = Ah@Bh + Ah@Bl + Al@Bh, each 16x16x32 bf16 MFMA, fp32 acc
//   -> ~4e-6 relative error, routing-safe (plain bf16 would flip top-2).
// LN fused to emit (hi,lo) bf16 pair; attention epilogue emits (hi,lo).
// Attention QK^T/PV still fp32 (round-4 target). ffn LDS stride 32->40
// u16 to kill 8-way bank conflicts on bf16x8 frag loads.
// =====================================================================
#define JAX_THREEFRY_PARTITIONABLE 1

typedef unsigned short u16;
typedef __attribute__((ext_vector_type(8))) short bf16x8;   // 8 bf16 = 4 VGPR
typedef __attribute__((ext_vector_type(4))) float f32x4;

__device__ __forceinline__ int imin_(int a, int b) { return a < b ? a : b; }

__device__ __forceinline__ u16 f2bf_(float f) {  // RNE float->bf16
  unsigned u = __float_as_uint(f);
  return (u16)((u + 0x7fffu + ((u >> 16) & 1u)) >> 16);
}
__device__ __forceinline__ float bf2f_(u16 h) {
  return __uint_as_float(((unsigned)h) << 16);
}

// ---------------- threefry2x32 (JAX-exact, 20 rounds) ----------------
__device__ __forceinline__ unsigned rotl32_(unsigned v, int d) {
  return (v << d) | (v >> (32 - d));
}

__device__ __forceinline__ void threefry2x32_(unsigned k0, unsigned k1,
                                              unsigned x0, unsigned x1,
                                              unsigned& o0, unsigned& o1) {
  unsigned ks2 = k0 ^ k1 ^ 0x1BD11BDAu;
  x0 += k0; x1 += k1;
#define TF_R(rot) { x0 += x1; x1 = rotl32_(x1, rot); x1 ^= x0; }
  TF_R(13) TF_R(15) TF_R(26) TF_R(6)
  x0 += k1;  x1 += ks2 + 1u;
  TF_R(17) TF_R(29) TF_R(16) TF_R(24)
  x0 += ks2; x1 += k0 + 2u;
  TF_R(13) TF_R(15) TF_R(26) TF_R(6)
  x0 += k0;  x1 += k1 + 3u;
  TF_R(17) TF_R(29) TF_R(16) TF_R(24)
  x0 += k1;  x1 += ks2 + 4u;
  TF_R(13) TF_R(15) TF_R(26) TF_R(6)
  x0 += ks2; x1 += k0 + 5u;
#undef TF_R
  o0 = x0; o1 = x1;
}

// XLA ErfInv32 (Giles polynomial) — matches lax.erf_inv on f32.
__device__ float erfinv_f32_(float x) {
  float w = -log1pf(-x * x);
  float p;
  if (w < 5.0f) {
    w -= 2.5f;
    p = 2.81022636e-08f;
    p = fmaf(p, w, 3.43273939e-07f);
    p = fmaf(p, w, -3.5233877e-06f);
    p = fmaf(p, w, -4.39150654e-06f);
    p = fmaf(p, w, 0.00021858087f);
    p = fmaf(p, w, -0.00125372503f);
    p = fmaf(p, w, -0.00417768164f);
    p = fmaf(p, w, 0.246640727f);
    p = fmaf(p, w, 1.50140941f);
  } else {
    w = sqrtf(w) - 3.0f;
    p = -0.000200214257f;
    p = fmaf(p, w, 0.000100950558f);
    p = fmaf(p, w, 0.00134934322f);
    p = fmaf(p, w, -0.00367342844f);
    p = fmaf(p, w, 0.00573950773f);
    p = fmaf(p, w, -0.0076224613f);
    p = fmaf(p, w, 0.00943887047f);
    p = fmaf(p, w, 1.00167406f);
    p = fmaf(p, w, 2.83297682f);
  }
  return p * x;
}

__device__ float bits_to_normal_(unsigned b) {
  const float lo = -0.99999994f;  // nextafter(-1, 0) in f32
  float f = __uint_as_float((b >> 9) | 0x3f800000u) - 1.0f;  // [0,1)
  float u = fmaxf(lo, f * 2.0f + lo);
  return 1.41421356237f * erfinv_f32_(u);
}

// normals for logits shape (2,1024,8) -> 16384 elems, key = (0,42)
__global__ __launch_bounds__(256) void noise_kernel(float* __restrict__ normals) {
  int i = blockIdx.x * 256 + threadIdx.x;
#if JAX_THREEFRY_PARTITIONABLE
  if (i < 16384) {
    unsigned o0, o1;
    threefry2x32_(0u, 42u, 0u, (unsigned)i, o0, o1);
    normals[i] = bits_to_normal_(o0 ^ o1);
  }
#else
  if (i < 8192) {
    unsigned o0, o1;
    threefry2x32_(0u, 42u, (unsigned)i, (unsigned)(i + 8192), o0, o1);
    normals[i] = bits_to_normal_(o0);
    normals[i + 8192] = bits_to_normal_(o1);
  }
#endif
}

// ---------------- block reduce (256 threads, wave64) -----------------
__device__ float block_reduce_sum_(float v) {
  for (int m = 1; m <= 32; m <<= 1) v += __shfl_xor(v, m, 64);
  __shared__ float red[4];
  int lane = threadIdx.x & 63, w = threadIdx.x >> 6;
  if (lane == 0) red[w] = v;
  __syncthreads();
  v = red[0] + red[1] + red[2] + red[3];
  __syncthreads();
  return v;
}

// ---------------- LayerNorm (fp32 out) -------------------------------
__global__ __launch_bounds__(256) void ln_kernel(
    const float* __restrict__ X, const float* __restrict__ g,
    const float* __restrict__ bta, float* __restrict__ Y) {
  int row = blockIdx.x;
  int t = threadIdx.x;
  const float4* xr = (const float4*)(X + (size_t)row * 1024);
  float4 v = xr[t];
  float s = v.x + v.y + v.z + v.w;
  s = block_reduce_sum_(s);
  float mean = s * (1.0f / 1024.0f);
  float dx = v.x - mean, dy = v.y - mean, dz = v.z - mean, dw = v.w - mean;
  float sq = dx * dx + dy * dy + dz * dz + dw * dw;
  sq = block_reduce_sum_(sq);
  float rstd = 1.0f / sqrtf(sq * (1.0f / 1024.0f) + 1e-5f);
  float4 gv = ((const float4*)g)[t];
  float4 bv = ((const float4*)bta)[t];
  float4 y;
  y.x = dx * rstd * gv.x + bv.x;
  y.y = dy * rstd * gv.y + bv.y;
  y.z = dz * rstd * gv.z + bv.z;
  y.w = dw * rstd * gv.w + bv.w;
  ((float4*)(Y + (size_t)row * 1024))[t] = y;
}

// ---------------- LayerNorm emitting split bf16 (hi,lo) --------------
__global__ __launch_bounds__(256) void ln_split_kernel(
    const float* __restrict__ X, const float* __restrict__ g,
    const float* __restrict__ bta, u16* __restrict__ Yh,
    u16* __restrict__ Yl) {
  int row = blockIdx.x;
  int t = threadIdx.x;
  const float4* xr = (const float4*)(X + (size_t)row * 1024);
  float4 v = xr[t];
  float s = v.x + v.y + v.z + v.w;
  s = block_reduce_sum_(s);
  float mean = s * (1.0f / 1024.0f);
  float dx = v.x - mean, dy = v.y - mean, dz = v.z - mean, dw = v.w - mean;
  float sq = dx * dx + dy * dy + dz * dz + dw * dw;
  sq = block_reduce_sum_(sq);
  float rstd = 1.0f / sqrtf(sq * (1.0f / 1024.0f) + 1e-5f);
  float4 gv = ((const float4*)g)[t];
  float4 bv = ((const float4*)bta)[t];
  float y[4];
  y[0] = dx * rstd * gv.x + bv.x;
  y[1] = dy * rstd * gv.y + bv.y;
  y[2] = dz * rstd * gv.z + bv.z;
  y[3] = dw * rstd * gv.w + bv.w;
  ushort4 h, l;
  u16* hp = (u16*)&h; u16* lp = (u16*)&l;
#pragma unroll
  for (int j = 0; j < 4; ++j) {
    u16 hh = f2bf_(y[j]);
    hp[j] = hh;
    lp[j] = f2bf_(y[j] - bf2f_(hh));
  }
  *(ushort4*)(Yh + (size_t)row * 1024 + t * 4) = h;
  *(ushort4*)(Yl + (size_t)row * 1024 + t * 4) = l;
}

// ---------------- fp32 -> (hi,lo) bf16 split, 4 elems/thread ---------
__global__ __launch_bounds__(256) void cvt_split_kernel(
    const float* __restrict__ src, u16* __restrict__ hi,
    u16* __restrict__ lo) {
  int i = (blockIdx.x * 256 + threadIdx.x) * 4;
  float4 v = *(const float4*)(src + i);
  float a[4] = {v.x, v.y, v.z, v.w};
  ushort4 h, l;
  u16* hp = (u16*)&h; u16* lp = (u16*)&l;
#pragma unroll
  for (int j = 0; j < 4; ++j) {
    u16 hh = f2bf_(a[j]);
    hp[j] = hh;
    lp[j] = f2bf_(a[j] - bf2f_(hh));
  }
  *(ushort4*)(hi + i) = h;
  *(ushort4*)(lo + i) = l;
}

// ============ split-bf16 MFMA GEMM: C = A @ W^T + bias (+resid) ======
// A: (hi,lo) bf16 [M][K] k-contig. W: (hi,lo) bf16 [N][K] k-contig.
// 128x128 tile, BK=32, 4 waves (2x2), each wave 4x4 frags of 16x16x32.
// 3 MFMA terms per frag pair: Ah*Bh + Ah*Bl + Al*Bh (fp32 acc).
// LDS row stride 40 u16 (80 B): frag b128 reads 2-way aliased = free.
template<bool RESID>
__global__ __launch_bounds__(256) void split_gemm_nt(
    const u16* __restrict__ Ah, const u16* __restrict__ Al,
    const u16* __restrict__ Wh, const u16* __restrict__ Wl,
    const float* __restrict__ bias, const float* __restrict__ resid,
    float* __restrict__ C, int M, int N, int K) {
  __shared__ __align__(16) u16 Ahs[128 * 40];
  __shared__ __align__(16) u16 Als[128 * 40];
  __shared__ __align__(16) u16 Bhs[128 * 40];
  __shared__ __align__(16) u16 Bls[128 * 40];
  const int t = threadIdx.x;
  const int n0 = blockIdx.x * 128, m0 = blockIdx.y * 128;
  const int lane = t & 63, wv = t >> 6;
  const int wm = (wv & 1) * 64, wn = (wv >> 1) * 64;
  const int col = lane & 15, quad = lane >> 4;
  f32x4 acc[4][4] = {};
  const int r = t >> 1, kh = (t & 1) * 16;
  const u16* pah = Ah + (size_t)(m0 + r) * K + kh;
  const u16* pal = Al + (size_t)(m0 + r) * K + kh;
  const u16* pwh = Wh + (size_t)(n0 + r) * K + kh;
  const u16* pwl = Wl + (size_t)(n0 + r) * K + kh;
  for (int k0 = 0; k0 < K; k0 += 32) {
    uint4 a0 = *(const uint4*)(pah), a1 = *(const uint4*)(pah + 8);
    uint4 b0 = *(const uint4*)(pal), b1 = *(const uint4*)(pal + 8);
    uint4 c0 = *(const uint4*)(pwh), c1 = *(const uint4*)(pwh + 8);
    uint4 d0 = *(const uint4*)(pwl), d1 = *(const uint4*)(pwl + 8);
    pah += 32; pal += 32; pwh += 32; pwl += 32;
    *(uint4*)&Ahs[r * 40 + kh] = a0; *(uint4*)&Ahs[r * 40 + kh + 8] = a1;
    *(uint4*)&Als[r * 40 + kh] = b0; *(uint4*)&Als[r * 40 + kh + 8] = b1;
    *(uint4*)&Bhs[r * 40 + kh] = c0; *(uint4*)&Bhs[r * 40 + kh + 8] = c1;
    *(uint4*)&Bls[r * 40 + kh] = d0; *(uint4*)&Bls[r * 40 + kh + 8] = d1;
    __syncthreads();
    bf16x8 afh[4], afl[4], bfh[4], bfl[4];
#pragma unroll
    for (int i = 0; i < 4; ++i) {
      afh[i] = *(const bf16x8*)&Ahs[(wm + i * 16 + col) * 40 + quad * 8];
      afl[i] = *(const bf16x8*)&Als[(wm + i * 16 + col) * 40 + quad * 8];
    }
#pragma unroll
    for (int j = 0; j < 4; ++j) {
      bfh[j] = *(const bf16x8*)&Bhs[(wn + j * 16 + col) * 40 + quad * 8];
      bfl[j] = *(const bf16x8*)&Bls[(wn + j * 16 + col) * 40 + quad * 8];
    }
#pragma unroll
    for (int i = 0; i < 4; ++i) {
#pragma unroll
      for (int j = 0; j < 4; ++j) {
        acc[i][j] = __builtin_amdgcn_mfma_f32_16x16x32_bf16(afh[i], bfh[j], acc[i][j], 0, 0, 0);
        acc[i][j] = __builtin_amdgcn_mfma_f32_16x16x32_bf16(afh[i], bfl[j], acc[i][j], 0, 0, 0);
        acc[i][j] = __builtin_amdgcn_mfma_f32_16x16x32_bf16(afl[i], bfh[j], acc[i][j], 0, 0, 0);
      }
    }
    __syncthreads();
  }
  float bv[4];
#pragma unroll
  for (int j = 0; j < 4; ++j) bv[j] = bias[n0 + wn + j * 16 + col];
#pragma unroll
  for (int i = 0; i < 4; ++i) {
#pragma unroll
    for (int rr = 0; rr < 4; ++rr) {
      int m = m0 + wm + i * 16 + quad * 4 + rr;
      float* crow = C + (size_t)m * N;
      const float* rrow = RESID ? (resid + (size_t)m * N) : nullptr;
#pragma unroll
      for (int j = 0; j < 4; ++j) {
        int n = n0 + wn + j * 16 + col;
        float v = acc[i][j][rr] + bv[j];
        if (RESID) v += rrow[n];
        crow[n] = v;
      }
    }
  }
}

// ---------------- flash attention, fp32, DH=64 -----------------------
// Emits (hi,lo) bf16 split output for the following split GEMM.
__global__ __launch_bounds__(256) void attn_kernel(
    const float* __restrict__ QP, const float* __restrict__ KP,
    const float* __restrict__ VP, u16* __restrict__ AOh,
    u16* __restrict__ AOl, int nq, int nkv) {
  __shared__ float qs[64][68];
  __shared__ float kst[64][68];
  __shared__ float vs[64][68];
  __shared__ float ps[64][68];
  const int t = threadIdx.x;
  const int tx = t & 15, ty = t >> 4;
  const int bh = blockIdx.x;
  const int b = bh >> 4, h = bh & 15;
  const int q0 = blockIdx.y * 64;
  {
    int r = t >> 2, c = (t & 3) * 16;
    const float* src = QP + (size_t)(b * nq + q0 + r) * 1024 + h * 64 + c;
#pragma unroll
    for (int j = 0; j < 4; ++j) {
      float4 v = *(const float4*)(src + 4 * j);
      v.x *= 0.125f; v.y *= 0.125f; v.z *= 0.125f; v.w *= 0.125f;
      *(float4*)&qs[r][c + 4 * j] = v;
    }
  }
  float o[4][4] = {};
  float mi[4] = {-INFINITY, -INFINITY, -INFINITY, -INFINITY};
  float li[4] = {};
  for (int kv0 = 0; kv0 < nkv; kv0 += 64) {
    {
      int r = t >> 2, c = (t & 3) * 16;
      const float* ksrc = KP + (size_t)(b * nkv + kv0 + r) * 1024 + h * 64 + c;
      const float* vsrc = VP + (size_t)(b * nkv + kv0 + r) * 1024 + h * 64 + c;
#pragma unroll
      for (int j = 0; j < 4; ++j) {
        float4 kvv = *(const float4*)(ksrc + 4 * j);
        kst[c + 4 * j + 0][r] = kvv.x;
        kst[c + 4 * j + 1][r] = kvv.y;
        kst[c + 4 * j + 2][r] = kvv.z;
        kst[c + 4 * j + 3][r] = kvv.w;
        *(float4*)&vs[r][c + 4 * j] = *(const float4*)(vsrc + 4 * j);
      }
    }
    __syncthreads();
    float s[4][4] = {};
#pragma unroll
    for (int d = 0; d < 64; d += 4) {
      float qa[4][4], kb[4][4];
#pragma unroll
      for (int i = 0; i < 4; ++i) *(float4*)qa[i] = *(const float4*)&qs[ty * 4 + i][d];
#pragma unroll
      for (int dd = 0; dd < 4; ++dd) *(float4*)kb[dd] = *(const float4*)&kst[d + dd][tx * 4];
#pragma unroll
      for (int i = 0; i < 4; ++i) {
#pragma unroll
        for (int j = 0; j < 4; ++j) {
#pragma unroll
          for (int dd = 0; dd < 4; ++dd) s[i][j] += qa[i][dd] * kb[dd][j];
        }
      }
    }
    float al[4];
#pragma unroll
    for (int i = 0; i < 4; ++i) {
      float rm = fmaxf(fmaxf(s[i][0], s[i][1]), fmaxf(s[i][2], s[i][3]));
      rm = fmaxf(rm, __shfl_xor(rm, 1, 64));
      rm = fmaxf(rm, __shfl_xor(rm, 2, 64));
      rm = fmaxf(rm, __shfl_xor(rm, 4, 64));
      rm = fmaxf(rm, __shfl_xor(rm, 8, 64));
      float mnew = fmaxf(mi[i], rm);
      al[i] = __expf(mi[i] - mnew);
      float rs = 0.0f;
#pragma unroll
      for (int j = 0; j < 4; ++j) { s[i][j] = __expf(s[i][j] - mnew); rs += s[i][j]; }
      rs += __shfl_xor(rs, 1, 64);
      rs += __shfl_xor(rs, 2, 64);
      rs += __shfl_xor(rs, 4, 64);
      rs += __shfl_xor(rs, 8, 64);
      li[i] = li[i] * al[i] + rs;
      mi[i] = mnew;
      *(float4*)&ps[ty * 4 + i][tx * 4] = *(float4*)s[i];
    }
#pragma unroll
    for (int i = 0; i < 4; ++i) {
#pragma unroll
      for (int j = 0; j < 4; ++j) o[i][j] *= al[i];
    }
    __syncthreads();
#pragma unroll
    for (int kkk = 0; kkk < 64; kkk += 4) {
      float pa[4][4], vb[4][4];
#pragma unroll
      for (int i = 0; i < 4; ++i) *(float4*)pa[i] = *(const float4*)&ps[ty * 4 + i][kkk];
#pragma unroll
      for (int dd = 0; dd < 4; ++dd) *(float4*)vb[dd] = *(const float4*)&vs[kkk + dd][tx * 4];
#pragma unroll
      for (int i = 0; i < 4; ++i) {
#pragma unroll
        for (int j = 0; j < 4; ++j) {
#pragma unroll
          for (int dd = 0; dd < 4; ++dd) o[i][j] += pa[i][dd] * vb[dd][j];
        }
      }
    }
    __syncthreads();
  }
#pragma unroll
  for (int i = 0; i < 4; ++i) {
    float inv = 1.0f / li[i];
    ushort4 hv, lv;
    u16* hp = (u16*)&hv; u16* lp = (u16*)&lv;
#pragma unroll
    for (int j = 0; j < 4; ++j) {
      float v = o[i][j] * inv;
      u16 hh = f2bf_(v);
      hp[j] = hh;
      lp[j] = f2bf_(v - bf2f_(hh));
    }
    size_t idx = (size_t)(b * nq + q0 + ty * 4 + i) * 1024 + h * 64 + tx * 4;
    *(ushort4*)(AOh + idx) = hv;
    *(ushort4*)(AOl + idx) = lv;
  }
}

// ---------------- router: logits & noise_logits (N=8 each) -----------
__global__ __launch_bounds__(256) void router_kernel(
    const float* __restrict__ xm, const float* __restrict__ rw,
    const float* __restrict__ rb, const float* __restrict__ nw,
    const float* __restrict__ nb, float* __restrict__ logits,
    float* __restrict__ nlogits) {
  int row = blockIdx.x, t = threadIdx.x;
  const float* x = xm + (size_t)row * 1024;
  float accl[8] = {}, accn[8] = {};
  for (int d = t; d < 1024; d += 256) {
    float xv = x[d];
#pragma unroll
    for (int e = 0; e < 8; ++e) {
      accl[e] += xv * rw[e * 1024 + d];
      accn[e] += xv * nw[e * 1024 + d];
    }
  }
  __shared__ float red[16][4];
  int lane = t & 63, w = t >> 6;
#pragma unroll
  for (int e = 0; e < 8; ++e) {
    float v = accl[e];
    for (int m = 1; m <= 32; m <<= 1) v += __shfl_xor(v, m, 64);
    if (lane == 0) red[e][w] = v;
    float v2 = accn[e];
    for (int m = 1; m <= 32; m <<= 1) v2 += __shfl_xor(v2, m, 64);
    if (lane == 0) red[8 + e][w] = v2;
  }
  __syncthreads();
  if (t < 8)
    logits[row * 8 + t] = red[t][0] + red[t][1] + red[t][2] + red[t][3] + rb[t];
  else if (t < 16)
    nlogits[row * 8 + t - 8] =
        red[t][0] + red[t][1] + red[t][2] + red[t][3] + nb[t - 8];
}

// ---------------- routing: noisy top-2, probs, expert counts ---------
__global__ __launch_bounds__(256) void route_kernel(
    const float* __restrict__ logits, const float* __restrict__ nlogits,
    const float* __restrict__ normals, int* __restrict__ routei,
    float* __restrict__ routep, int* __restrict__ cnt) {
  int bt = blockIdx.x * 256 + threadIdx.x;
  if (bt >= 2048) return;
  float noisy[8];
#pragma unroll
  for (int e = 0; e < 8; ++e) {
    float nl = nlogits[bt * 8 + e];
    float sp = fmaxf(nl, 0.0f) + log1pf(expf(-fabsf(nl)));  // softplus
    noisy[e] = logits[bt * 8 + e] + normals[bt * 8 + e] * sp;
  }
  int i1 = 0; float n1 = noisy[0];
#pragma unroll
  for (int e = 1; e < 8; ++e) if (noisy[e] > n1) { n1 = noisy[e]; i1 = e; }
  int i2 = -1; float n2 = -INFINITY;
#pragma unroll
  for (int e = 0; e < 8; ++e)
    if (e != i1 && noisy[e] > n2) { n2 = noisy[e]; i2 = e; }
  float e2 = expf(n2 - n1);
  float denom = 1.0f + e2;
  routei[bt * 2 + 0] = i1; routei[bt * 2 + 1] = i2;
  routep[bt * 2 + 0] = 1.0f / denom; routep[bt * 2 + 1] = e2 / denom;
  atomicAdd(&cnt[i1], 1);
  atomicAdd(&cnt[i2], 1);
}

__global__ void zero_kernel(int* __restrict__ cnt) {
  if (threadIdx.x < 8) cnt[threadIdx.x] = 0;
}

__global__ void offs_kernel(const int* __restrict__ cnt, int* __restrict__ offs,
                            int* __restrict__ fill) {
  if (threadIdx.x == 0 && blockIdx.x == 0) {
    int o = 0;
    for (int e = 0; e < 8; ++e) { offs[e] = o; o += cnt[e]; fill[e] = 0; }
  }
}

__global__ __launch_bounds__(256) void fill_kernel(
    const int* __restrict__ routei, const float* __restrict__ routep,
    const int* __restrict__ offs, int* __restrict__ fill,
    int* __restrict__ alist, float* __restrict__ aprob) {
  int bt = blockIdx.x * 256 + threadIdx.x;
  if (bt >= 2048) return;
#pragma unroll
  for (int s = 0; s < 2; ++s) {
    int e = routei[bt * 2 + s];
    int pos = offs[e] + atomicAdd(&fill[e], 1);
    alist[pos] = bt;
    aprob[pos] = routep[bt * 2 + s];
  }
}

__global__ __launch_bounds__(256) void copy_kernel(const float* __restrict__ src,
                                                   float* __restrict__ dst) {
  int i = blockIdx.x * 256 + threadIdx.x;
  ((float4*)dst)[i] = ((const float4*)src)[i];
}

// fp32 -> bf16 convert (hi only), 4 elems/thread
__global__ __launch_bounds__(256) void f2bf_kernel(const float* __restrict__ src,
                                                   u16* __restrict__ dst) {
  int i = (blockIdx.x * 256 + threadIdx.x) * 4;
  float4 v = *(const float4*)(src + i);
  ushort4 o;
  o.x = f2bf_(v.x); o.y = f2bf_(v.y); o.z = f2bf_(v.z); o.w = f2bf_(v.w);
  *(ushort4*)(dst + i) = o;
}

__device__ __forceinline__ float gelu_exact_(float x) {
  return 0.5f * x * (1.0f + erff(x * 0.70710678f));
}

// ===================== bf16 MFMA expert GEMMs ========================
// Same tile as split_gemm but single-term bf16 (output-only precision).
// LDS row stride 40 u16 to avoid 8-way frag-load bank conflicts.
__global__ __launch_bounds__(256) void ffn1_mfma(
    const u16* __restrict__ Xb, const float* __restrict__ W1,
    const float* __restrict__ B1, u16* __restrict__ H,
    const int* __restrict__ alist, const int* __restrict__ cnt,
    const int* __restrict__ offs) {
  const int e = blockIdx.z;
  const int ce = cnt[e];
  const int m0 = blockIdx.y * 128;
  if (m0 >= ce) return;
  const int off = offs[e];
  const int n0 = blockIdx.x * 128;
  const float* W = W1 + (size_t)e * (1024 * 4096);
  __shared__ __align__(16) u16 As[128 * 40];
  __shared__ __align__(16) u16 Bs[128 * 40];
  const int t = threadIdx.x;
  const int lane = t & 63, wv = t >> 6;
  const int wm = (wv & 1) * 64, wn = (wv >> 1) * 64;
  const int col = lane & 15, quad = lane >> 4;
  f32x4 acc[4][4] = {};
  const int ar = t >> 1, ak = (t & 1) * 16;
  const int arow = alist[off + imin_(m0 + ar, ce - 1)];
  const u16* asrc = Xb + (size_t)arow * 1024 + ak;
  const int bn = t >> 1, bk = (t & 1) * 16;
  const float* wsrc = W + (size_t)bk * 4096 + n0 + bn;
  for (int k0 = 0; k0 < 1024; k0 += 32) {
    uint4 a0 = *(const uint4*)(asrc);
    uint4 a1 = *(const uint4*)(asrc + 8);
    u16 ub[16];
#pragma unroll
    for (int kk = 0; kk < 16; ++kk) ub[kk] = f2bf_(wsrc[(size_t)kk * 4096]);
    asrc += 32;
    wsrc += (size_t)32 * 4096;
    *(uint4*)&As[ar * 40 + ak] = a0;
    *(uint4*)&As[ar * 40 + ak + 8] = a1;
    *(uint4*)&Bs[bn * 40 + bk] = *(uint4*)&ub[0];
    *(uint4*)&Bs[bn * 40 + bk + 8] = *(uint4*)&ub[8];
    __syncthreads();
    bf16x8 af[4], bf[4];
#pragma unroll
    for (int i = 0; i < 4; ++i)
      af[i] = *(const bf16x8*)&As[(wm + i * 16 + col) * 40 + quad * 8];
#pragma unroll
    for (int j = 0; j < 4; ++j)
      bf[j] = *(const bf16x8*)&Bs[(wn + j * 16 + col) * 40 + quad * 8];
#pragma unroll
    for (int i = 0; i < 4; ++i)
#pragma unroll
      for (int j = 0; j < 4; ++j)
        acc[i][j] = __builtin_amdgcn_mfma_f32_16x16x32_bf16(af[i], bf[j], acc[i][j], 0, 0, 0);
    __syncthreads();
  }
#pragma unroll
  for (int j = 0; j < 4; ++j) {
    int n = n0 + wn + j * 16 + col;
    float bv = B1[(size_t)e * 4096 + n];
#pragma unroll
    for (int i = 0; i < 4; ++i) {
#pragma unroll
      for (int r = 0; r < 4; ++r) {
        int m = m0 + wm + i * 16 + quad * 4 + r;
        if (m < ce) {
          float v = gelu_exact_(acc[i][j][r] + bv);
          H[(size_t)(off + m) * 4096 + n] = f2bf_(v);
        }
      }
    }
  }
}

__global__ __launch_bounds__(256) void ffn2_mfma(
    const u16* __restrict__ H, const float* __restrict__ W2,
    const float* __restrict__ B2, float* __restrict__ Out,
    const int* __restrict__ alist, const float* __restrict__ aprob,
    const int* __restrict__ cnt, const int* __restrict__ offs) {
  const int e = blockIdx.z;
  const int ce = cnt[e];
  const int m0 = blockIdx.y * 128;
  if (m0 >= ce) return;
  const int off = offs[e];
  const int n0 = blockIdx.x * 128;
  const float* W = W2 + (size_t)e * (4096 * 1024);
  __shared__ __align__(16) u16 As[128 * 40];
  __shared__ __align__(16) u16 Bs[128 * 40];
  const int t = threadIdx.x;
  const int lane = t & 63, wv = t >> 6;
  const int wm = (wv & 1) * 64, wn = (wv >> 1) * 64;
  const int col = lane & 15, quad = lane >> 4;
  f32x4 acc[4][4] = {};
  const int ar = t >> 1, ak = (t & 1) * 16;
  const u16* asrc = H + (size_t)(off + imin_(m0 + ar, ce - 1)) * 4096 + ak;
  const int bn = t >> 1, bk = (t & 1) * 16;
  const float* wsrc = W + (size_t)bk * 1024 + n0 + bn;
  for (int k0 = 0; k0 < 4096; k0 += 32) {
    uint4 a0 = *(const uint4*)(asrc);
    uint4 a1 = *(const uint4*)(asrc + 8);
    u16 ub[16];
#pragma unroll
    for (int kk = 0; kk < 16; ++kk) ub[kk] = f2bf_(wsrc[(size_t)kk * 1024]);
    asrc += 32;
    wsrc += (size_t)32 * 1024;
    *(uint4*)&As[ar * 40 + ak] = a0;
    *(uint4*)&As[ar * 40 + ak + 8] = a1;
    *(uint4*)&Bs[bn * 40 + bk] = *(uint4*)&ub[0];
    *(uint4*)&Bs[bn * 40 + bk + 8] = *(uint4*)&ub[8];
    __syncthreads();
    bf16x8 af[4], bf[4];
#pragma unroll
    for (int i = 0; i < 4; ++i)
      af[i] = *(const bf16x8*)&As[(wm + i * 16 + col) * 40 + quad * 8];
#pragma unroll
    for (int j = 0; j < 4; ++j)
      bf[j] = *(const bf16x8*)&Bs[(wn + j * 16 + col) * 40 + quad * 8];
#pragma unroll
    for (int i = 0; i < 4; ++i)
#pragma unroll
      for (int j = 0; j < 4; ++j)
        acc[i][j] = __builtin_amdgcn_mfma_f32_16x16x32_bf16(af[i], bf[j], acc[i][j], 0, 0, 0);
    __syncthreads();
  }
  float bv[4];
#pragma unroll
  for (int j = 0; j < 4; ++j) bv[j] = B2[(size_t)e * 1024 + n0 + wn + j * 16 + col];
#pragma unroll
  for (int i = 0; i < 4; ++i) {
#pragma unroll
    for (int r = 0; r < 4; ++r) {
      int m = m0 + wm + i * 16 + quad * 4 + r;
      if (m < ce) {
        int aidx = off + m;
        int tok = alist[aidx];
        float p = aprob[aidx];
        float* orow = Out + (size_t)tok * 1024;
#pragma unroll
        for (int j = 0; j < 4; ++j) {
          int n = n0 + wn + j * 16 + col;
          atomicAdd(&orow[n], p * (acc[i][j][r] + bv[j]));
        }
      }
    }
  }
}

// =====================================================================
extern "C" void kernel_launch(void* const* d_in, const int* in_sizes, int n_in,
                              void* d_out, int out_size, void* d_ws, size_t ws_size,
                              hipStream_t stream) {
  (void)in_sizes; (void)n_in; (void)out_size; (void)ws_size;
  const float* q        = (const float*)d_in[0];
  const float* kv       = (const float*)d_in[1];
  const float* ln_cq_g  = (const float*)d_in[2];
  const float* ln_cq_b  = (const float*)d_in[3];
  const float* ln_ckv_g = (const float*)d_in[4];
  const float* ln_ckv_b = (const float*)d_in[5];
  const float* ln_s_g   = (const float*)d_in[6];
  const float* ln_s_b   = (const float*)d_in[7];
  const float* ln_m_g   = (const float*)d_in[8];
  const float* ln_m_b   = (const float*)d_in[9];
  const float* ca_in_w  = (const float*)d_in[10];
  const float* ca_in_b  = (const float*)d_in[11];
  const float* ca_out_w = (const float*)d_in[12];
  const float* ca_out_b = (const float*)d_in[13];
  const float* sa_in_w  = (const float*)d_in[14];
  const float* sa_in_b  = (const float*)d_in[15];
  const float* sa_out_w = (const float*)d_in[16];
  const float* sa_out_b = (const float*)d_in[17];
  const float* moe_rw   = (const float*)d_in[18];
  const float* moe_rb   = (const float*)d_in[19];
  const float* moe_nw   = (const float*)d_in[20];
  const float* moe_nb   = (const float*)d_in[21];
  const float* moe_w1   = (const float*)d_in[22];
  const float* moe_b1   = (const float*)d_in[23];
  const float* moe_w2   = (const float*)d_in[24];
  const float* moe_b2   = (const float*)d_in[25];
  float* out = (float*)d_out;

  // -------- workspace layout (floats). Peak ~112.5 MB. --------
  float* ws = (float*)d_ws;
  const size_t MEG = 1u << 20;
  float* x1   = ws;               // 2M fl
  float* x2   = ws + 2 * MEG;     // 2M fl
  float* xm   = ws + 4 * MEG;     // 2M fl
  u16*   aoh  = (u16*)(ws + 6 * MEG);  // 2M el (attn out hi)
  u16*   aol  = (u16*)(ws + 7 * MEG);  // 2M el (attn out lo)
  float* misc = ws + 8 * MEG;
  float* normals = misc;                      // 16384
  float* logits  = misc + 16384;              // 16384
  float* nlogits = misc + 32768;              // 16384
  float* routep  = misc + 49152;              // 4096
  float* aprob   = misc + 53248;              // 4096
  int*   routei  = (int*)(misc + 57344);      // 4096
  int*   alist   = (int*)(misc + 61440);      // 4096
  int*   cnt     = (int*)(misc + 65536);      // 8
  int*   offs    = cnt + 8;                   // 8
  int*   fillc   = cnt + 16;                  // 8
  float* RA = ws + 8 * MEG + 131072;          // 20M fl, phase-reused
  // attn phases:
  u16*   w1h = (u16*)RA;                    // 3M el (in-proj weights hi)
  u16*   w1l = (u16*)(RA + (3 * MEG) / 2);  // 3M el
  u16*   w2h = (u16*)(RA + 3 * MEG);        // 1M el (out-proj hi)
  u16*   w2l = (u16*)(RA + 3 * MEG + MEG / 2);
  u16*   a1h = (u16*)(RA + 4 * MEG);        // 2M el (lnq / xs hi)
  u16*   a1l = (u16*)(RA + 5 * MEG);
  u16*   a2h = (u16*)(RA + 6 * MEG);        // 4M el (lnkv hi; cross only)
  u16*   a2l = (u16*)(RA + 8 * MEG);
  float* qp  = RA + 10 * MEG;               // 2M fl
  float* kp  = RA + 12 * MEG;               // 4M fl (self: 2M)
  float* vp  = RA + 16 * MEG;               // 4M fl (self: 2M)
  // moe phase:
  u16*   xb  = (u16*)RA;                    // 2M el bf16
  u16*   hb  = (u16*)(RA + 1 * MEG);        // 16M el bf16

  dim3 blk(256);

  zero_kernel<<<dim3(1), blk, 0, stream>>>(cnt);
  noise_kernel<<<dim3(64), blk, 0, stream>>>(normals);

  // ---- cross attention ----
  cvt_split_kernel<<<dim3(3072), blk, 0, stream>>>(ca_in_w, w1h, w1l);
  cvt_split_kernel<<<dim3(1024), blk, 0, stream>>>(ca_out_w, w2h, w2l);
  ln_split_kernel<<<dim3(2048), blk, 0, stream>>>(q, ln_cq_g, ln_cq_b, a1h, a1l);
  ln_split_kernel<<<dim3(4096), blk, 0, stream>>>(kv, ln_ckv_g, ln_ckv_b, a2h, a2l);
  split_gemm_nt<false><<<dim3(8, 16), blk, 0, stream>>>(
      a1h, a1l, w1h, w1l, ca_in_b, nullptr, qp, 2048, 1024, 1024);
  split_gemm_nt<false><<<dim3(8, 32), blk, 0, stream>>>(
      a2h, a2l, w1h + MEG, w1l + MEG, ca_in_b + 1024, nullptr, kp, 4096, 1024, 1024);
  split_gemm_nt<false><<<dim3(8, 32), blk, 0, stream>>>(
      a2h, a2l, w1h + 2 * MEG, w1l + 2 * MEG, ca_in_b + 2048, nullptr, vp, 4096, 1024, 1024);
  attn_kernel<<<dim3(32, 16), blk, 0, stream>>>(qp, kp, vp, aoh, aol, 1024, 2048);
  split_gemm_nt<true><<<dim3(8, 16), blk, 0, stream>>>(
      aoh, aol, w2h, w2l, ca_out_b, q, x1, 2048, 1024, 1024);

  // ---- self attention ----
  cvt_split_kernel<<<dim3(3072), blk, 0, stream>>>(sa_in_w, w1h, w1l);
  cvt_split_kernel<<<dim3(1024), blk, 0, stream>>>(sa_out_w, w2h, w2l);
  ln_split_kernel<<<dim3(2048), blk, 0, stream>>>(x1, ln_s_g, ln_s_b, a1h, a1l);
  split_gemm_nt<false><<<dim3(8, 16), blk, 0, stream>>>(
      a1h, a1l, w1h, w1l, sa_in_b, nullptr, qp, 2048, 1024, 1024);
  split_gemm_nt<false><<<dim3(8, 16), blk, 0, stream>>>(
      a1h, a1l, w1h + MEG, w1l + MEG, sa_in_b + 1024, nullptr, kp, 2048, 1024, 1024);
  split_gemm_nt<false><<<dim3(8, 16), blk, 0, stream>>>(
      a1h, a1l, w1h + 2 * MEG, w1l + 2 * MEG, sa_in_b + 2048, nullptr, vp, 2048, 1024, 1024);
  attn_kernel<<<dim3(32, 16), blk, 0, stream>>>(qp, kp, vp, aoh, aol, 1024, 1024);
  split_gemm_nt<true><<<dim3(8, 16), blk, 0, stream>>>(
      aoh, aol, w2h, w2l, sa_out_b, x1, x2, 2048, 1024, 1024);

  // ---- MoE ----
  ln_kernel<<<dim3(2048), blk, 0, stream>>>(x2, ln_m_g, ln_m_b, xm);
  f2bf_kernel<<<dim3(2048), blk, 0, stream>>>(xm, xb);
  router_kernel<<<dim3(2048), blk, 0, stream>>>(xm, moe_rw, moe_rb, moe_nw, moe_nb, logits, nlogits);
  route_kernel<<<dim3(8), blk, 0, stream>>>(logits, nlogits, normals, routei, routep, cnt);
  offs_kernel<<<dim3(1), blk, 0, stream>>>(cnt, offs, fillc);
  fill_kernel<<<dim3(8), blk, 0, stream>>>(routei, routep, offs, fillc, alist, aprob);
  copy_kernel<<<dim3(2048), blk, 0, stream>>>(x2, out);  // residual base
  ffn1_mfma<<<dim3(32, 16, 8), blk, 0, stream>>>(xb, moe_w1, moe_b1, hb, alist, cnt, offs);
  ffn2_mfma<<<dim3(8, 16, 8), blk, 0, stream>>>(hb, moe_w2, moe_b2, out, alist, aprob, cnt, offs);
}